// Round 1
// baseline (2949.040 us; speedup 1.0000x reference)
//
#include <hip/hip_runtime.h>
#include <math.h>

#define BB 2
#define TT 2048
#define DD 512
#define LL 4
#define HH 8
#define HDD 64
#define SEMN 50
#define CLIPN 512
#define NTOK (BB*TT)   // 4096

// ---------------- embedding + cond matvec + pos ----------------
__global__ void embed_kernel(const int* __restrict__ idx, const float* __restrict__ clip,
                             const float* __restrict__ tok0, const float* __restrict__ tok1,
                             const float* __restrict__ cw, const float* __restrict__ cb,
                             const float* __restrict__ pos, float* __restrict__ x) {
  int row = blockIdx.x;           // 0..NTOK-1
  int b = row / TT, t = row % TT;
  int d = threadIdx.x;            // 512 threads
  float e;
  if (t == 0) {
    float acc = cb[d];
    for (int c = 0; c < CLIPN; ++c) acc = fmaf(clip[b*CLIPN + c], cw[c*DD + d], acc);
    e = acc;
  } else {
    int tok = idx[b*(TT-1) + (t-1)];
    e = (t <= SEMN) ? tok0[(size_t)tok*DD + d] : tok1[(size_t)tok*DD + d];
  }
  x[(size_t)row*DD + d] = e + pos[(size_t)t*DD + d];
}

// ---------------- layernorm (row per block, 256 threads) ----------------
__global__ __launch_bounds__(256) void ln_kernel(const float* __restrict__ x,
                                                 const float* __restrict__ g,
                                                 const float* __restrict__ bta,
                                                 float* __restrict__ out) {
  int row = blockIdx.x;
  int tid = threadIdx.x;
  const float* xr = x + (size_t)row * DD;
  float v0 = xr[tid], v1 = xr[tid + 256];
  __shared__ float red[4];
  float s = v0 + v1;
  #pragma unroll
  for (int off = 32; off > 0; off >>= 1) s += __shfl_down(s, off);
  if ((tid & 63) == 0) red[tid >> 6] = s;
  __syncthreads();
  float mean = (red[0] + red[1] + red[2] + red[3]) * (1.0f / DD);
  float d0 = v0 - mean, d1 = v1 - mean;
  float sv = d0*d0 + d1*d1;
  #pragma unroll
  for (int off = 32; off > 0; off >>= 1) sv += __shfl_down(sv, off);
  __syncthreads();
  if ((tid & 63) == 0) red[tid >> 6] = sv;
  __syncthreads();
  float var = (red[0] + red[1] + red[2] + red[3]) * (1.0f / DD);
  float r = rsqrtf(var + 1e-5f);
  out[(size_t)row*DD + tid]       = d0 * r * g[tid]       + bta[tid];
  out[(size_t)row*DD + tid + 256] = d1 * r * g[tid + 256] + bta[tid + 256];
}

// ---------------- fp32 tiled GEMM: C = A[M,K] @ W[K,N] + bias (+res) (gelu?) ----------------
template<int RESID, int GELU>
__global__ __launch_bounds__(256) void gemm_kernel(
    const float* __restrict__ A, const float* __restrict__ W,
    const float* __restrict__ bias, const float* __restrict__ res,
    float* __restrict__ C, int M, int N, int K) {
  __shared__ float As[16][68];  // [k][m]
  __shared__ float Bs[16][68];  // [k][n]
  int tid = threadIdx.x;
  int row0 = blockIdx.y << 6, col0 = blockIdx.x << 6;
  int tr = tid >> 4, tc = tid & 15;
  int am = tid >> 2, ak = (tid & 3) << 2;
  int bk = tid >> 4, bn = (tid & 15) << 2;
  float acc[4][4] = {};
  for (int k0 = 0; k0 < K; k0 += 16) {
    float4 a4 = *(const float4*)&A[(size_t)(row0 + am)*K + k0 + ak];
    As[ak+0][am] = a4.x; As[ak+1][am] = a4.y; As[ak+2][am] = a4.z; As[ak+3][am] = a4.w;
    *(float4*)&Bs[bk][bn] = *(const float4*)&W[(size_t)(k0 + bk)*N + col0 + bn];
    __syncthreads();
    #pragma unroll
    for (int k = 0; k < 16; ++k) {
      float4 av = *(const float4*)&As[k][tr << 2];
      float4 bv = *(const float4*)&Bs[k][tc << 2];
      float a[4] = {av.x, av.y, av.z, av.w};
      float b[4] = {bv.x, bv.y, bv.z, bv.w};
      #pragma unroll
      for (int i = 0; i < 4; ++i)
        #pragma unroll
        for (int j = 0; j < 4; ++j)
          acc[i][j] = fmaf(a[i], b[j], acc[i][j]);
    }
    __syncthreads();
  }
  #pragma unroll
  for (int i = 0; i < 4; ++i) {
    int r = row0 + (tr << 2) + i;
    #pragma unroll
    for (int j = 0; j < 4; ++j) {
      int c = col0 + (tc << 2) + j;
      float val = acc[i][j] + bias[c];
      if (RESID) val += res[(size_t)r*N + c];
      if (GELU) val = 0.5f * val * (1.0f + erff(val * 0.70710678118f));
      C[(size_t)r*N + c] = val;
    }
  }
}

// ---------------- flash-style causal attention, BQ=BK=64, HD=64 ----------------
__global__ __launch_bounds__(256) void attn_kernel(
    const float* __restrict__ q, const float* __restrict__ k,
    const float* __restrict__ v, float* __restrict__ y) {
  __shared__ float Qs[64][68];  // [d][r]
  __shared__ float Ks[64][68];  // [d][c]
  __shared__ float Vs[64][68];  // [key][d]
  __shared__ float Ps[64][68];  // [key][r]
  __shared__ float mS[64], lS[64];
  int qt = blockIdx.x, h = blockIdx.y, b = blockIdx.z;
  int tid = threadIdx.x;
  int tr = tid >> 4, tc = tid & 15;
  int lr = tid >> 4;
  int ld = (tid & 15) << 2;
  int q0 = qt << 6;
  const size_t hoff = (size_t)h * HDD;
  #pragma unroll
  for (int i = 0; i < 4; ++i) {
    int r = lr + (i << 4);
    float4 qa = *(const float4*)&q[((size_t)(b*TT + q0 + r))*DD + hoff + ld];
    Qs[ld+0][r] = qa.x; Qs[ld+1][r] = qa.y; Qs[ld+2][r] = qa.z; Qs[ld+3][r] = qa.w;
  }
  if (tid < 64) { mS[tid] = -1e30f; lS[tid] = 0.0f; }
  float o[4][4] = {};
  int nkt = qt + 1;
  for (int kt = 0; kt < nkt; ++kt) {
    __syncthreads();
    #pragma unroll
    for (int i = 0; i < 4; ++i) {
      int r = lr + (i << 4);
      float4 ka = *(const float4*)&k[((size_t)(b*TT + (kt<<6) + r))*DD + hoff + ld];
      Ks[ld+0][r] = ka.x; Ks[ld+1][r] = ka.y; Ks[ld+2][r] = ka.z; Ks[ld+3][r] = ka.w;
      float4 va = *(const float4*)&v[((size_t)(b*TT + (kt<<6) + r))*DD + hoff + ld];
      *(float4*)&Vs[r][ld] = va;
    }
    __syncthreads();
    float s[4][4] = {};
    for (int d = 0; d < 64; ++d) {
      float4 qv = *(const float4*)&Qs[d][tr << 2];
      float4 kv = *(const float4*)&Ks[d][tc << 2];
      float qa[4] = {qv.x, qv.y, qv.z, qv.w};
      float ka[4] = {kv.x, kv.y, kv.z, kv.w};
      #pragma unroll
      for (int i = 0; i < 4; ++i)
        #pragma unroll
        for (int j = 0; j < 4; ++j)
          s[i][j] = fmaf(qa[i], ka[j], s[i][j]);
    }
    const float sc = 0.125f;  // 1/sqrt(64)
    if (kt == qt) {
      #pragma unroll
      for (int i = 0; i < 4; ++i)
        #pragma unroll
        for (int j = 0; j < 4; ++j)
          s[i][j] = ((tc<<2)+j <= (tr<<2)+i) ? s[i][j]*sc : -1e30f;
    } else {
      #pragma unroll
      for (int i = 0; i < 4; ++i)
        #pragma unroll
        for (int j = 0; j < 4; ++j)
          s[i][j] *= sc;
    }
    #pragma unroll
    for (int i = 0; i < 4; ++i) {
      int rloc = (tr << 2) + i;
      float rm = fmaxf(fmaxf(s[i][0], s[i][1]), fmaxf(s[i][2], s[i][3]));
      #pragma unroll
      for (int off = 1; off < 16; off <<= 1) rm = fmaxf(rm, __shfl_xor(rm, off, 16));
      float mo = mS[rloc];
      float mn = fmaxf(mo, rm);
      float rsum = 0.0f;
      #pragma unroll
      for (int j = 0; j < 4; ++j) {
        float p = __expf(s[i][j] - mn);
        Ps[(tc<<2)+j][rloc] = p;
        rsum += p;
      }
      #pragma unroll
      for (int off = 1; off < 16; off <<= 1) rsum += __shfl_xor(rsum, off, 16);
      float fac = __expf(mo - mn);
      #pragma unroll
      for (int j = 0; j < 4; ++j) o[i][j] *= fac;
      if (tc == 0) {
        mS[rloc] = mn;
        lS[rloc] = lS[rloc]*fac + rsum;
      }
    }
    __syncthreads();
    for (int j = 0; j < 64; ++j) {
      float4 pv = *(const float4*)&Ps[j][tr << 2];
      float4 vv = *(const float4*)&Vs[j][tc << 2];
      float pa[4] = {pv.x, pv.y, pv.z, pv.w};
      float va[4] = {vv.x, vv.y, vv.z, vv.w};
      #pragma unroll
      for (int i = 0; i < 4; ++i)
        #pragma unroll
        for (int c = 0; c < 4; ++c)
          o[i][c] = fmaf(pa[i], va[c], o[i][c]);
    }
  }
  #pragma unroll
  for (int i = 0; i < 4; ++i) {
    float inv = 1.0f / lS[(tr << 2) + i];
    float4 outv;
    outv.x = o[i][0]*inv; outv.y = o[i][1]*inv; outv.z = o[i][2]*inv; outv.w = o[i][3]*inv;
    *(float4*)&y[((size_t)(b*TT + q0 + (tr<<2)+i))*DD + hoff + (tc<<2)] = outv;
  }
}

extern "C" void kernel_launch(void* const* d_in, const int* in_sizes, int n_in,
                              void* d_out, int out_size, void* d_ws, size_t ws_size,
                              hipStream_t stream) {
  const int*   idx    = (const int*)d_in[0];
  const float* clip   = (const float*)d_in[1];
  const float* tok0   = (const float*)d_in[2];
  const float* tok1   = (const float*)d_in[3];
  const float* cond_w = (const float*)d_in[4];
  const float* cond_b = (const float*)d_in[5];
  const float* pos    = (const float*)d_in[6];
  const float* ln1_g  = (const float*)d_in[7];
  const float* ln1_b  = (const float*)d_in[8];
  const float* wq     = (const float*)d_in[9];
  const float* bq     = (const float*)d_in[10];
  const float* wk     = (const float*)d_in[11];
  const float* bk     = (const float*)d_in[12];
  const float* wv     = (const float*)d_in[13];
  const float* bv     = (const float*)d_in[14];
  const float* wo     = (const float*)d_in[15];
  const float* bo     = (const float*)d_in[16];
  const float* ln2_g  = (const float*)d_in[17];
  const float* ln2_b  = (const float*)d_in[18];
  const float* w1     = (const float*)d_in[19];
  const float* b1     = (const float*)d_in[20];
  const float* w2     = (const float*)d_in[21];
  const float* b2     = (const float*)d_in[22];

  float* x  = (float*)d_out;            // (B,T,D) activation, in-place residual stream
  float* ws = (float*)d_ws;
  const size_t SLOT = (size_t)NTOK * DD;   // 2M floats
  float* h   = ws;                 // 0..2M   (ln out; later reused for y? no: h2)
  float* qb  = ws + SLOT;          // 2..4M
  float* kb  = ws + 2*SLOT;        // 4..6M
  float* vb  = ws + 3*SLOT;        // 6..8M
  float* yb  = ws + 4*SLOT;        // 8..10M
  float* ffn = ws + SLOT;          // 2..10M (8M floats; q,k,v,y dead by then)

  embed_kernel<<<dim3(NTOK), 512, 0, stream>>>(idx, clip, tok0, tok1, cond_w, cond_b, pos, x);

  for (int i = 0; i < LL; ++i) {
    ln_kernel<<<NTOK, 256, 0, stream>>>(x, ln1_g + i*DD, ln1_b + i*DD, h);
    gemm_kernel<0,0><<<dim3(DD/64, NTOK/64), 256, 0, stream>>>(
        h, wq + (size_t)i*DD*DD, bq + i*DD, nullptr, qb, NTOK, DD, DD);
    gemm_kernel<0,0><<<dim3(DD/64, NTOK/64), 256, 0, stream>>>(
        h, wk + (size_t)i*DD*DD, bk + i*DD, nullptr, kb, NTOK, DD, DD);
    gemm_kernel<0,0><<<dim3(DD/64, NTOK/64), 256, 0, stream>>>(
        h, wv + (size_t)i*DD*DD, bv + i*DD, nullptr, vb, NTOK, DD, DD);
    attn_kernel<<<dim3(TT/64, HH, BB), 256, 0, stream>>>(qb, kb, vb, yb);
    gemm_kernel<1,0><<<dim3(DD/64, NTOK/64), 256, 0, stream>>>(
        yb, wo + (size_t)i*DD*DD, bo + i*DD, x, x, NTOK, DD, DD);
    ln_kernel<<<NTOK, 256, 0, stream>>>(x, ln2_g + i*DD, ln2_b + i*DD, h);
    gemm_kernel<0,1><<<dim3(4*DD/64, NTOK/64), 256, 0, stream>>>(
        h, w1 + (size_t)i*DD*4*DD, b1 + (size_t)i*4*DD, nullptr, ffn, NTOK, 4*DD, DD);
    gemm_kernel<1,0><<<dim3(DD/64, NTOK/64), 256, 0, stream>>>(
        ffn, w2 + (size_t)i*4*DD*DD, b2 + i*DD, x, x, NTOK, DD, 4*DD);
  }
}

// Round 2
// 939.211 us; speedup vs baseline: 3.1399x; 3.1399x over previous
//
#include <hip/hip_runtime.h>
#include <math.h>

#define BB 2
#define TT 2048
#define DD 512
#define LL 4
#define HH 8
#define HDD 64
#define SEMN 50
#define CLIPN 512
#define NTOK (BB*TT)   // 4096

typedef __bf16 bf16x8 __attribute__((ext_vector_type(8)));
typedef __bf16 bf16x4 __attribute__((ext_vector_type(4)));
typedef float  f32x4  __attribute__((ext_vector_type(4)));

// ---------------- embedding + cond matvec + pos (fp32 out) ----------------
__global__ void embed_kernel(const int* __restrict__ idx, const float* __restrict__ clip,
                             const float* __restrict__ tok0, const float* __restrict__ tok1,
                             const float* __restrict__ cw, const float* __restrict__ cb,
                             const float* __restrict__ pos, float* __restrict__ x) {
  int row = blockIdx.x;
  int b = row / TT, t = row % TT;
  int d = threadIdx.x;
  float e;
  if (t == 0) {
    float acc = cb[d];
    for (int c = 0; c < CLIPN; ++c) acc = fmaf(clip[b*CLIPN + c], cw[c*DD + d], acc);
    e = acc;
  } else {
    int tok = idx[b*(TT-1) + (t-1)];
    e = (t <= SEMN) ? tok0[(size_t)tok*DD + d] : tok1[(size_t)tok*DD + d];
  }
  x[(size_t)row*DD + d] = e + pos[(size_t)t*DD + d];
}

// ---------------- layernorm: fp32 in -> bf16 out ----------------
__global__ __launch_bounds__(256) void ln_kernel(const float* __restrict__ x,
                                                 const float* __restrict__ g,
                                                 const float* __restrict__ bta,
                                                 __bf16* __restrict__ out) {
  int row = blockIdx.x;
  int tid = threadIdx.x;
  const float* xr = x + (size_t)row * DD;
  float v0 = xr[tid], v1 = xr[tid + 256];
  __shared__ float red[4];
  float s = v0 + v1;
  #pragma unroll
  for (int off = 32; off > 0; off >>= 1) s += __shfl_down(s, off);
  if ((tid & 63) == 0) red[tid >> 6] = s;
  __syncthreads();
  float mean = (red[0] + red[1] + red[2] + red[3]) * (1.0f / DD);
  float d0 = v0 - mean, d1 = v1 - mean;
  float sv = d0*d0 + d1*d1;
  #pragma unroll
  for (int off = 32; off > 0; off >>= 1) sv += __shfl_down(sv, off);
  __syncthreads();
  if ((tid & 63) == 0) red[tid >> 6] = sv;
  __syncthreads();
  float var = (red[0] + red[1] + red[2] + red[3]) * (1.0f / DD);
  float r = rsqrtf(var + 1e-5f);
  out[(size_t)row*DD + tid]       = (__bf16)(d0 * r * g[tid]       + bta[tid]);
  out[(size_t)row*DD + tid + 256] = (__bf16)(d1 * r * g[tid + 256] + bta[tid + 256]);
}

// ---------------- per-layer weight transpose+convert: [K,N] f32 -> [N,K] bf16 ----------------
__global__ __launch_bounds__(256) void prep_kernel(
    const float* __restrict__ wq, const float* __restrict__ wk,
    const float* __restrict__ wv, const float* __restrict__ wo,
    const float* __restrict__ w1, const float* __restrict__ w2,
    __bf16* __restrict__ wbuf) {
  __shared__ float tile[32][33];
  int id = blockIdx.x;
  const float* src; __bf16* dst; int K, N, t;
  if (id < 1024) {
    int m = id >> 8; t = id & 255;
    src = (m==0) ? wq : (m==1) ? wk : (m==2) ? wv : wo;
    dst = wbuf + (size_t)m * 262144; K = 512; N = 512;
  } else if (id < 2048) {
    t = id - 1024; src = w1; dst = wbuf + 1048576; K = 512; N = 2048;
  } else {
    t = id - 2048; src = w2; dst = wbuf + 2097152; K = 2048; N = 512;
  }
  int nsh = (N == 2048) ? 6 : 4;
  int tk = t >> nsh, tn = t & ((1 << nsh) - 1);
  int k0 = tk << 5, n0 = tn << 5;
  int tid = threadIdx.x;
  int r = tid >> 3, c = (tid & 7) << 2;
  float4 v = *(const float4*)&src[(size_t)(k0 + r)*N + n0 + c];
  tile[r][c+0] = v.x; tile[r][c+1] = v.y; tile[r][c+2] = v.z; tile[r][c+3] = v.w;
  __syncthreads();
  bf16x4 o;
  o[0] = (__bf16)tile[c+0][r];
  o[1] = (__bf16)tile[c+1][r];
  o[2] = (__bf16)tile[c+2][r];
  o[3] = (__bf16)tile[c+3][r];
  *(bf16x4*)&dst[(size_t)(n0 + r)*K + k0 + c] = o;
}

// ---------------- bf16 MFMA GEMM: C[M,N] = A[M,K] @ Bt[N,K]^T + bias (+res)(gelu) ----------------
template<int OB, int RES, int GEL>
__global__ __launch_bounds__(256) void mgemm(
    const __bf16* __restrict__ A, const __bf16* __restrict__ Bt,
    const float* __restrict__ bias, const float* __restrict__ res,
    float* __restrict__ outF, __bf16* __restrict__ outB, int M, int N, int K) {
  __shared__ __bf16 As[128*32];
  __shared__ __bf16 Bs[128*32];
  int tid = threadIdx.x;
  int l = tid & 63, wave = tid >> 6;
  int wr = wave >> 1, wc = wave & 1;
  int l15 = l & 15, lg = l >> 4;
  int m0 = blockIdx.y << 7, n0 = blockIdx.x << 7;

  f32x4 acc[4][4];
  #pragma unroll
  for (int i = 0; i < 4; ++i)
    #pragma unroll
    for (int j = 0; j < 4; ++j)
      acc[i][j] = (f32x4){0.f, 0.f, 0.f, 0.f};

  // staging: thread covers row srow (0..127), logical kslots {sh, sh+1}
  int srow = tid >> 1;
  int sh = (tid & 1) << 1;
  int swz = (srow >> 1) & 3;
  int p0 = ((sh + 0) ^ swz) << 3;   // element offset of physical slot
  int p1 = ((sh + 1) ^ swz) << 3;
  const __bf16* Ag = A  + (size_t)(m0 + srow)*K + (sh << 3);
  const __bf16* Bg = Bt + (size_t)(n0 + srow)*K + (sh << 3);
  __bf16* Aw = &As[srow*32];
  __bf16* Bw = &Bs[srow*32];

  for (int k0 = 0; k0 < K; k0 += 32) {
    bf16x8 a0 = *(const bf16x8*)(Ag + k0);
    bf16x8 a1 = *(const bf16x8*)(Ag + k0 + 8);
    bf16x8 b0 = *(const bf16x8*)(Bg + k0);
    bf16x8 b1 = *(const bf16x8*)(Bg + k0 + 8);
    __syncthreads();   // previous tile fully consumed
    *(bf16x8*)(Aw + p0) = a0;
    *(bf16x8*)(Aw + p1) = a1;
    *(bf16x8*)(Bw + p0) = b0;
    *(bf16x8*)(Bw + p1) = b1;
    __syncthreads();

    bf16x8 af[4], bfr[4];
    #pragma unroll
    for (int mi = 0; mi < 4; ++mi) {
      int row = (wr << 6) + (mi << 4) + l15;
      int ks = lg ^ ((row >> 1) & 3);
      af[mi] = *(const bf16x8*)&As[row*32 + (ks << 3)];
    }
    #pragma unroll
    for (int ni = 0; ni < 4; ++ni) {
      int row = (wc << 6) + (ni << 4) + l15;
      int ks = lg ^ ((row >> 1) & 3);
      bfr[ni] = *(const bf16x8*)&Bs[row*32 + (ks << 3)];
    }
    #pragma unroll
    for (int mi = 0; mi < 4; ++mi)
      #pragma unroll
      for (int ni = 0; ni < 4; ++ni)
        acc[mi][ni] = __builtin_amdgcn_mfma_f32_16x16x32_bf16(af[mi], bfr[ni], acc[mi][ni], 0, 0, 0);
  }

  #pragma unroll
  for (int mi = 0; mi < 4; ++mi) {
    #pragma unroll
    for (int ni = 0; ni < 4; ++ni) {
      int col = n0 + (wc << 6) + (ni << 4) + l15;
      float bs = bias[col];
      #pragma unroll
      for (int r = 0; r < 4; ++r) {
        int row = m0 + (wr << 6) + (mi << 4) + (lg << 2) + r;
        float v = acc[mi][ni][r] + bs;
        if (RES) v += res[(size_t)row*N + col];
        if (GEL) v = 0.5f * v * (1.0f + erff(v * 0.70710678118654752f));
        if (OB) outB[(size_t)row*N + col] = (__bf16)v;
        else    outF[(size_t)row*N + col] = v;
      }
    }
  }
}

// ---------------- MFMA flash attention, bf16 in/out, 4 waves x 16 q-rows, KBLK=64 ----------------
__global__ __launch_bounds__(256) void attn_kernel(
    const __bf16* __restrict__ q, const __bf16* __restrict__ k,
    const __bf16* __restrict__ v, __bf16* __restrict__ y) {
  __shared__ __bf16 Ks[64*64];      // [key][hd], slot-swizzled
  __shared__ __bf16 Vt[64*64];      // [hd][key], swizzled
  __shared__ __bf16 Pw[4][16*64];   // per wave [q][key], swizzled
  int qt = blockIdx.x, hh = blockIdx.y, b = blockIdx.z;
  int tid = threadIdx.x, l = tid & 63, wave = tid >> 6;
  int l15 = l & 15, lg = l >> 4;
  size_t rowbase = (size_t)(b*TT + qt*64);
  int hoff = hh * HDD;

  // Q fragments (A-operand): row = l15, k = lg*8.., two hd-halves
  bf16x8 qf[2];
  {
    size_t qrow = (rowbase + wave*16 + l15) * DD + hoff;
    qf[0] = *(const bf16x8*)&q[qrow + lg*8];
    qf[1] = *(const bf16x8*)&q[qrow + 32 + lg*8];
  }

  f32x4 o[4];
  #pragma unroll
  for (int hc = 0; hc < 4; ++hc) o[hc] = (f32x4){0.f,0.f,0.f,0.f};
  float m[4], ls[4];
  #pragma unroll
  for (int r = 0; r < 4; ++r) { m[r] = -1e30f; ls[r] = 0.f; }

  int srow = tid >> 2;            // staging key/row 0..63
  int sls  = (tid & 3) << 1;      // logical 16B slots {sls, sls+1}
  __bf16* PwW = Pw[wave];
  int qpos0 = qt*64 + wave*16 + lg*4;

  for (int kt = 0; kt <= qt; ++kt) {
    __syncthreads();
    size_t kro = (size_t)(b*TT + kt*64 + srow) * DD + hoff;
    bf16x8 kv0 = *(const bf16x8*)&k[kro + sls*8];
    bf16x8 kv1 = *(const bf16x8*)&k[kro + sls*8 + 8];
    bf16x8 vv0 = *(const bf16x8*)&v[kro + sls*8];
    bf16x8 vv1 = *(const bf16x8*)&v[kro + sls*8 + 8];
    *(bf16x8*)&Ks[srow*64 + (((sls+0) ^ (srow & 7)) << 3)] = kv0;
    *(bf16x8*)&Ks[srow*64 + (((sls+1) ^ (srow & 7)) << 3)] = kv1;
    #pragma unroll
    for (int e = 0; e < 8; ++e) {
      int hd0 = sls*8 + e, hd1 = sls*8 + 8 + e;
      Vt[(hd0*64 + srow) ^ ((hd0 & 7) << 3)] = vv0[e];
      Vt[(hd1*64 + srow) ^ ((hd1 & 7) << 3)] = vv1[e];
    }
    __syncthreads();

    // S = Q @ K^T  (C: row=q=lg*4+r, col=key=kc*16+l15)
    float sv[4][4];
    #pragma unroll
    for (int kc = 0; kc < 4; ++kc) {
      int key = kc*16 + l15;
      f32x4 sa = (f32x4){0.f,0.f,0.f,0.f};
      bf16x8 kf0 = *(const bf16x8*)&Ks[(key*64 + (0*4 + lg)*8) ^ ((key & 7) << 3)];
      bf16x8 kf1 = *(const bf16x8*)&Ks[(key*64 + (1*4 + lg)*8) ^ ((key & 7) << 3)];
      sa = __builtin_amdgcn_mfma_f32_16x16x32_bf16(qf[0], kf0, sa, 0, 0, 0);
      sa = __builtin_amdgcn_mfma_f32_16x16x32_bf16(qf[1], kf1, sa, 0, 0, 0);
      #pragma unroll
      for (int r = 0; r < 4; ++r) sv[kc][r] = sa[r];
    }

    // mask + scale
    int kbase = kt*64;
    #pragma unroll
    for (int kc = 0; kc < 4; ++kc) {
      int kpos = kbase + kc*16 + l15;
      #pragma unroll
      for (int r = 0; r < 4; ++r)
        sv[kc][r] = (kpos <= qpos0 + r) ? sv[kc][r] * 0.125f : -1e30f;
    }

    // online softmax (rows live in 16-lane groups sharing lg)
    float fac[4];
    #pragma unroll
    for (int r = 0; r < 4; ++r) {
      float mx = fmaxf(fmaxf(sv[0][r], sv[1][r]), fmaxf(sv[2][r], sv[3][r]));
      #pragma unroll
      for (int off = 1; off < 16; off <<= 1) mx = fmaxf(mx, __shfl_xor(mx, off, 16));
      float mn = fmaxf(m[r], mx);
      fac[r] = __expf(m[r] - mn);
      m[r] = mn;
    }
    float rs[4] = {0.f, 0.f, 0.f, 0.f};
    #pragma unroll
    for (int kc = 0; kc < 4; ++kc) {
      #pragma unroll
      for (int r = 0; r < 4; ++r) {
        float p = __expf(sv[kc][r] - m[r]);
        rs[r] += p;
        int qr = lg*4 + r;
        PwW[(qr*64 + kc*16 + l15) ^ ((qr & 7) << 3)] = (__bf16)p;
      }
    }
    #pragma unroll
    for (int r = 0; r < 4; ++r) {
      #pragma unroll
      for (int off = 1; off < 16; off <<= 1) rs[r] += __shfl_xor(rs[r], off, 16);
      ls[r] = ls[r] * fac[r] + rs[r];
    }
    #pragma unroll
    for (int hc = 0; hc < 4; ++hc)
      #pragma unroll
      for (int r = 0; r < 4; ++r) o[hc][r] *= fac[r];

    asm volatile("s_waitcnt lgkmcnt(0)" ::: "memory");

    // O += P @ V  (A: row=q=l15, k=key; B: col=hd, k=key)
    bf16x8 pa0 = *(const bf16x8*)&PwW[(l15*64 +  0 + lg*8) ^ ((l15 & 7) << 3)];
    bf16x8 pa1 = *(const bf16x8*)&PwW[(l15*64 + 32 + lg*8) ^ ((l15 & 7) << 3)];
    #pragma unroll
    for (int hc = 0; hc < 4; ++hc) {
      int hd = hc*16 + l15;
      bf16x8 vf0 = *(const bf16x8*)&Vt[(hd*64 +  0 + lg*8) ^ ((hd & 7) << 3)];
      bf16x8 vf1 = *(const bf16x8*)&Vt[(hd*64 + 32 + lg*8) ^ ((hd & 7) << 3)];
      o[hc] = __builtin_amdgcn_mfma_f32_16x16x32_bf16(pa0, vf0, o[hc], 0, 0, 0);
      o[hc] = __builtin_amdgcn_mfma_f32_16x16x32_bf16(pa1, vf1, o[hc], 0, 0, 0);
    }
  }

  #pragma unroll
  for (int r = 0; r < 4; ++r) {
    float inv = 1.0f / ls[r];
    size_t rowg = (rowbase + wave*16 + lg*4 + r) * DD + hoff;
    #pragma unroll
    for (int hc = 0; hc < 4; ++hc)
      y[rowg + hc*16 + l15] = (__bf16)(o[hc][r] * inv);
  }
}

extern "C" void kernel_launch(void* const* d_in, const int* in_sizes, int n_in,
                              void* d_out, int out_size, void* d_ws, size_t ws_size,
                              hipStream_t stream) {
  const int*   idx    = (const int*)d_in[0];
  const float* clip   = (const float*)d_in[1];
  const float* tok0   = (const float*)d_in[2];
  const float* tok1   = (const float*)d_in[3];
  const float* cond_w = (const float*)d_in[4];
  const float* cond_b = (const float*)d_in[5];
  const float* pos    = (const float*)d_in[6];
  const float* ln1_g  = (const float*)d_in[7];
  const float* ln1_b  = (const float*)d_in[8];
  const float* wq     = (const float*)d_in[9];
  const float* bq     = (const float*)d_in[10];
  const float* wk     = (const float*)d_in[11];
  const float* bk     = (const float*)d_in[12];
  const float* wv     = (const float*)d_in[13];
  const float* bv     = (const float*)d_in[14];
  const float* wo     = (const float*)d_in[15];
  const float* bo     = (const float*)d_in[16];
  const float* ln2_g  = (const float*)d_in[17];
  const float* ln2_b  = (const float*)d_in[18];
  const float* w1     = (const float*)d_in[19];
  const float* b1     = (const float*)d_in[20];
  const float* w2     = (const float*)d_in[21];
  const float* b2     = (const float*)d_in[22];

  float* x = (float*)d_out;
  char* wsb = (char*)d_ws;
  __bf16* wbuf = (__bf16*)wsb;                       //  6,291,456 B (layer weights bf16 ^T)
  __bf16* h    = (__bf16*)(wsb + 6291456);           //  4 MB
  __bf16* qb   = (__bf16*)(wsb + 10485760);          //  4 MB
  __bf16* kb   = (__bf16*)(wsb + 14680064);          //  4 MB
  __bf16* vb   = (__bf16*)(wsb + 18874368);          //  4 MB
  __bf16* yb   = (__bf16*)(wsb + 23068672);          //  4 MB  (end 27,262,976)
  __bf16* ffn  = qb;                                 // 16 MB alias over qb..yb

  embed_kernel<<<dim3(NTOK), 512, 0, stream>>>(idx, clip, tok0, tok1, cond_w, cond_b, pos, x);

  for (int i = 0; i < LL; ++i) {
    prep_kernel<<<dim3(3072), 256, 0, stream>>>(
        wq + (size_t)i*262144, wk + (size_t)i*262144, wv + (size_t)i*262144,
        wo + (size_t)i*262144, w1 + (size_t)i*1048576, w2 + (size_t)i*1048576, wbuf);

    ln_kernel<<<NTOK, 256, 0, stream>>>(x, ln1_g + i*DD, ln1_b + i*DD, h);

    mgemm<1,0,0><<<dim3(4, 32), 256, 0, stream>>>(h, wbuf +       0, bq + i*DD, nullptr, nullptr, qb, NTOK, DD, DD);
    mgemm<1,0,0><<<dim3(4, 32), 256, 0, stream>>>(h, wbuf +  262144, bk + i*DD, nullptr, nullptr, kb, NTOK, DD, DD);
    mgemm<1,0,0><<<dim3(4, 32), 256, 0, stream>>>(h, wbuf +  524288, bv + i*DD, nullptr, nullptr, vb, NTOK, DD, DD);

    attn_kernel<<<dim3(TT/64, HH, BB), 256, 0, stream>>>(qb, kb, vb, yb);

    mgemm<0,1,0><<<dim3(4, 32), 256, 0, stream>>>(yb, wbuf +  786432, bo + i*DD, x, x, nullptr, NTOK, DD, DD);

    ln_kernel<<<NTOK, 256, 0, stream>>>(x, ln2_g + i*DD, ln2_b + i*DD, h);

    mgemm<1,0,1><<<dim3(16, 32), 256, 0, stream>>>(h, wbuf + 1048576, b1 + (size_t)i*4*DD, nullptr, nullptr, ffn, NTOK, 4*DD, DD);
    mgemm<0,1,0><<<dim3(4, 32), 256, 0, stream>>>(ffn, wbuf + 2097152, b2 + i*DD, x, x, nullptr, NTOK, DD, 4*DD);
  }
}

// Round 3
// 781.749 us; speedup vs baseline: 3.7724x; 1.2014x over previous
//
#include <hip/hip_runtime.h>
#include <math.h>

#define BB 2
#define TT 2048
#define DD 512
#define LL 4
#define HH 8
#define HDD 64
#define SEMN 50
#define CLIPN 512
#define NTOK (BB*TT)   // 4096
#define QS 1536        // fused qkv row stride

typedef __bf16 bf16x8 __attribute__((ext_vector_type(8)));
typedef __bf16 bf16x4 __attribute__((ext_vector_type(4)));
typedef float  f32x4  __attribute__((ext_vector_type(4)));

#if __has_builtin(__builtin_amdgcn_global_load_lds)
#define USE_GLL 1
#endif

__device__ __forceinline__ void gll16(const __bf16* g, __bf16* l) {
#ifdef USE_GLL
  __builtin_amdgcn_global_load_lds((const __attribute__((address_space(1))) void*)g,
                                   (__attribute__((address_space(3))) void*)l, 16, 0, 0);
#endif
}

// ---------------- embedding + cond matvec + pos (fp32 out) ----------------
__global__ void embed_kernel(const int* __restrict__ idx, const float* __restrict__ clip,
                             const float* __restrict__ tok0, const float* __restrict__ tok1,
                             const float* __restrict__ cw, const float* __restrict__ cb,
                             const float* __restrict__ pos, float* __restrict__ x) {
  int row = blockIdx.x;
  int b = row / TT, t = row % TT;
  int d = threadIdx.x;
  float e;
  if (t == 0) {
    float acc = cb[d];
    for (int c = 0; c < CLIPN; ++c) acc = fmaf(clip[b*CLIPN + c], cw[c*DD + d], acc);
    e = acc;
  } else {
    int tok = idx[b*(TT-1) + (t-1)];
    e = (t <= SEMN) ? tok0[(size_t)tok*DD + d] : tok1[(size_t)tok*DD + d];
  }
  x[(size_t)row*DD + d] = e + pos[(size_t)t*DD + d];
}

// ---------------- layernorm: fp32 in -> bf16 out ----------------
__global__ __launch_bounds__(256) void ln_kernel(const float* __restrict__ x,
                                                 const float* __restrict__ g,
                                                 const float* __restrict__ bta,
                                                 __bf16* __restrict__ out) {
  int row = blockIdx.x;
  int tid = threadIdx.x;
  const float* xr = x + (size_t)row * DD;
  float v0 = xr[tid], v1 = xr[tid + 256];
  __shared__ float red[4];
  float s = v0 + v1;
  #pragma unroll
  for (int off = 32; off > 0; off >>= 1) s += __shfl_down(s, off);
  if ((tid & 63) == 0) red[tid >> 6] = s;
  __syncthreads();
  float mean = (red[0] + red[1] + red[2] + red[3]) * (1.0f / DD);
  float d0 = v0 - mean, d1 = v1 - mean;
  float sv = d0*d0 + d1*d1;
  #pragma unroll
  for (int off = 32; off > 0; off >>= 1) sv += __shfl_down(sv, off);
  __syncthreads();
  if ((tid & 63) == 0) red[tid >> 6] = sv;
  __syncthreads();
  float var = (red[0] + red[1] + red[2] + red[3]) * (1.0f / DD);
  float r = rsqrtf(var + 1e-5f);
  out[(size_t)row*DD + tid]       = (__bf16)(d0 * r * g[tid]       + bta[tid]);
  out[(size_t)row*DD + tid + 256] = (__bf16)(d1 * r * g[tid + 256] + bta[tid + 256]);
}

// ---------------- per-layer weight transpose+convert: [K,N] f32 -> [N,K] bf16 ----------------
__global__ __launch_bounds__(256) void prep_kernel(
    const float* __restrict__ wq, const float* __restrict__ wk,
    const float* __restrict__ wv, const float* __restrict__ wo,
    const float* __restrict__ w1, const float* __restrict__ w2,
    __bf16* __restrict__ wbuf) {
  __shared__ float tile[32][33];
  int id = blockIdx.x;
  const float* src; __bf16* dst; int K, N, t;
  if (id < 1024) {
    int m = id >> 8; t = id & 255;
    src = (m==0) ? wq : (m==1) ? wk : (m==2) ? wv : wo;
    dst = wbuf + (size_t)m * 262144; K = 512; N = 512;
  } else if (id < 2048) {
    t = id - 1024; src = w1; dst = wbuf + 1048576; K = 512; N = 2048;
  } else {
    t = id - 2048; src = w2; dst = wbuf + 2097152; K = 2048; N = 512;
  }
  int nsh = (N == 2048) ? 6 : 4;
  int tk = t >> nsh, tn = t & ((1 << nsh) - 1);
  int k0 = tk << 5, n0 = tn << 5;
  int tid = threadIdx.x;
  int r = tid >> 3, c = (tid & 7) << 2;
  float4 v = *(const float4*)&src[(size_t)(k0 + r)*N + n0 + c];
  tile[r][c+0] = v.x; tile[r][c+1] = v.y; tile[r][c+2] = v.z; tile[r][c+3] = v.w;
  __syncthreads();
  bf16x4 o;
  o[0] = (__bf16)tile[c+0][r];
  o[1] = (__bf16)tile[c+1][r];
  o[2] = (__bf16)tile[c+2][r];
  o[3] = (__bf16)tile[c+3][r];
  *(bf16x4*)&dst[(size_t)(n0 + r)*K + k0 + c] = o;
}

// ---------------- bf16 MFMA GEMM: C[M,N] = A[M,K] @ Bt[N,K]^T ----------------
// TM in {128,64}; TN = 128 always. QKV3: 3-way bias. RES: +res fp32. GEL: gelu. OB: bf16 out.
template<int TM, int QKV3, int RES, int GEL, int OB>
__global__ __launch_bounds__(256) void mgemm(
    const __bf16* __restrict__ A, const __bf16* __restrict__ Bt,
    const float* __restrict__ b0, const float* __restrict__ b1p, const float* __restrict__ b2p,
    const float* __restrict__ res, float* __restrict__ outF, __bf16* __restrict__ outB,
    int M, int N, int K) {
  __shared__ __bf16 As[TM*32];
  __shared__ __bf16 Bs[128*32];
  int tid = threadIdx.x, wave = tid >> 6, l = tid & 63;
  int l15 = l & 15, lg = l >> 4;
  int m0 = blockIdx.y * TM, n0 = blockIdx.x << 7;
  constexpr int FM = 4;
  constexpr int FN = (TM == 128) ? 4 : 2;
  int wr = (TM == 128) ? (wave >> 1) : 0;
  int wc = (TM == 128) ? (wave & 1) : wave;

  f32x4 acc[FM][FN] = {};

  for (int k0 = 0; k0 < K; k0 += 32) {
#ifdef USE_GLL
    __syncthreads();    // previous tile consumed
    #pragma unroll
    for (int c = wave; c < TM/16; c += 4) {
      int row = c*16 + (l >> 2);
      int lslot = (l & 3) ^ ((row >> 1) & 3);
      gll16(A + (size_t)(m0+row)*K + k0 + lslot*8, &As[c*512]);
    }
    #pragma unroll
    for (int c = wave; c < 8; c += 4) {
      int row = c*16 + (l >> 2);
      int lslot = (l & 3) ^ ((row >> 1) & 3);
      gll16(Bt + (size_t)(n0+row)*K + k0 + lslot*8, &Bs[c*512]);
    }
    asm volatile("s_waitcnt vmcnt(0)" ::: "memory");
    __syncthreads();
#else
    bf16x8 ar[TM/64 > 0 ? TM/64 : 1], br[2];
    #pragma unroll
    for (int c = 0; c < TM/64; ++c) {
      int idx = tid + c*256;
      int row = idx >> 2;
      int lslot = (idx & 3) ^ ((row >> 1) & 3);
      ar[c] = *(const bf16x8*)(A + (size_t)(m0+row)*K + k0 + lslot*8);
    }
    #pragma unroll
    for (int c = 0; c < 2; ++c) {
      int idx = tid + c*256;
      int row = idx >> 2;
      int lslot = (idx & 3) ^ ((row >> 1) & 3);
      br[c] = *(const bf16x8*)(Bt + (size_t)(n0+row)*K + k0 + lslot*8);
    }
    __syncthreads();
    #pragma unroll
    for (int c = 0; c < TM/64; ++c) {
      int idx = tid + c*256;
      *(bf16x8*)&As[(idx >> 2)*32 + (idx & 3)*8] = ar[c];
    }
    #pragma unroll
    for (int c = 0; c < 2; ++c) {
      int idx = tid + c*256;
      *(bf16x8*)&Bs[(idx >> 2)*32 + (idx & 3)*8] = br[c];
    }
    __syncthreads();
#endif
    bf16x8 af[FM], bfr[FN];
    #pragma unroll
    for (int mi = 0; mi < FM; ++mi) {
      int row = (wr << 6) + (mi << 4) + l15;
      int ks = lg ^ ((row >> 1) & 3);
      af[mi] = *(const bf16x8*)&As[row*32 + (ks << 3)];
    }
    #pragma unroll
    for (int ni = 0; ni < FN; ++ni) {
      int row = wc*(FN*16) + (ni << 4) + l15;
      int ks = lg ^ ((row >> 1) & 3);
      bfr[ni] = *(const bf16x8*)&Bs[row*32 + (ks << 3)];
    }
    #pragma unroll
    for (int mi = 0; mi < FM; ++mi)
      #pragma unroll
      for (int ni = 0; ni < FN; ++ni)
        acc[mi][ni] = __builtin_amdgcn_mfma_f32_16x16x32_bf16(af[mi], bfr[ni], acc[mi][ni], 0, 0, 0);
  }

  #pragma unroll
  for (int mi = 0; mi < FM; ++mi) {
    #pragma unroll
    for (int ni = 0; ni < FN; ++ni) {
      int col = n0 + wc*(FN*16) + (ni << 4) + l15;
      float bs;
      if (QKV3) bs = (col < 512) ? b0[col] : (col < 1024) ? b1p[col-512] : b2p[col-1024];
      else bs = b0[col];
      #pragma unroll
      for (int r = 0; r < 4; ++r) {
        int row = m0 + (wr << 6) + (mi << 4) + (lg << 2) + r;
        float v = acc[mi][ni][r] + bs;
        if (RES) v += res[(size_t)row*N + col];
        if (GEL) v = 0.5f * v * (1.0f + erff(v * 0.70710678118654752f));
        if (OB) outB[(size_t)row*N + col] = (__bf16)v;
        else    outF[(size_t)row*N + col] = v;
      }
    }
  }
}

// ---------------- barrier-free flash attention: 1 wave = (b,h,16 q-rows), KB=32 ----------------
// swapped QK^T: S^T = mfma(A=K, B=Q); K direct-to-reg; V via wave-private LDS transpose.
__global__ __launch_bounds__(512) void attn_kernel(const __bf16* __restrict__ qkv,
                                                   __bf16* __restrict__ y) {
  __shared__ __bf16 lds[8 * 2560];   // per wave: Vt[64hd][32key] (2048) + P[16q][32key] (512)
  int tid = threadIdx.x;
  int wave = tid >> 6, l = tid & 63;
  int l15 = l & 15, lg = l >> 4;
  __bf16* Vt = &lds[wave * 2560];
  __bf16* Pl = &lds[wave * 2560 + 2048];

  int wid = blockIdx.x * 8 + wave;     // 0..2047, longest-first
  int g  = 127 - (wid >> 4);           // q-group (16 rows) within (b,h)
  int bh = wid & 15;
  int b = bh >> 3, h = bh & 7;

  const __bf16* qp = qkv + (size_t)(b*TT)*QS + h*HDD;
  const __bf16* kp = qp + 512;
  const __bf16* vp = qp + 1024;

  // Q B-fragment (col=q=l15, k=hd=lg*8+e), pre-scaled by 1/sqrt(64)
  bf16x8 qf0, qf1;
  {
    size_t qr = (size_t)(g*16 + l15) * QS;
    bf16x8 t0 = *(const bf16x8*)(qp + qr + lg*8);
    bf16x8 t1 = *(const bf16x8*)(qp + qr + 32 + lg*8);
    #pragma unroll
    for (int e = 0; e < 8; ++e) {
      qf0[e] = (__bf16)((float)t0[e] * 0.125f);
      qf1[e] = (__bf16)((float)t1[e] * 0.125f);
    }
  }

  f32x4 o[4] = {};
  float m = -1e30f, lsum = 0.f;
  int nt = (16*g + 47) >> 5;

  auto kload = [&](int kt, bf16x8& k00, bf16x8& k01, bf16x8& k10, bf16x8& k11,
                   bf16x8& v0, bf16x8& v1, bf16x8& v2, bf16x8& v3) {
    size_t r0 = (size_t)(kt*32 + l15) * QS;
    k00 = *(const bf16x8*)(kp + r0 + lg*8);
    k01 = *(const bf16x8*)(kp + r0 + 32 + lg*8);
    k10 = *(const bf16x8*)(kp + r0 + 16*QS + lg*8);
    k11 = *(const bf16x8*)(kp + r0 + 16*QS + 32 + lg*8);
    size_t vr = (size_t)(kt*32 + (l >> 1)) * QS + (l & 1)*32;
    v0 = *(const bf16x8*)(vp + vr);
    v1 = *(const bf16x8*)(vp + vr + 8);
    v2 = *(const bf16x8*)(vp + vr + 16);
    v3 = *(const bf16x8*)(vp + vr + 24);
  };

  auto process = [&](int kt, bf16x8 k00, bf16x8 k01, bf16x8 k10, bf16x8 k11,
                     bf16x8 v0, bf16x8 v1, bf16x8 v2, bf16x8 v3) {
    // V transpose into wave-private LDS: Vt[hd][key], slot-swizzled
    int key = l >> 1;
    int h0 = (l & 1) * 32;
    const bf16x8 vv0 = v0, vv1 = v1, vv2 = v2, vv3 = v3;
    #pragma unroll
    for (int e = 0; e < 8; ++e) {
      int hd;
      hd = h0 + e;      Vt[hd*32 + ((((key>>3) ^ (hd&3)) << 3) | (key & 7))] = vv0[e];
      hd = h0 + 8 + e;  Vt[hd*32 + ((((key>>3) ^ (hd&3)) << 3) | (key & 7))] = vv1[e];
      hd = h0 + 16 + e; Vt[hd*32 + ((((key>>3) ^ (hd&3)) << 3) | (key & 7))] = vv2[e];
      hd = h0 + 24 + e; Vt[hd*32 + ((((key>>3) ^ (hd&3)) << 3) | (key & 7))] = vv3[e];
    }

    // S^T = K @ Q^T : rows=key (kb*16+lg*4+r), cols=q (l15)
    f32x4 s0 = {}, s1 = {};
    s0 = __builtin_amdgcn_mfma_f32_16x16x32_bf16(k00, qf0, s0, 0, 0, 0);
    s0 = __builtin_amdgcn_mfma_f32_16x16x32_bf16(k01, qf1, s0, 0, 0, 0);
    s1 = __builtin_amdgcn_mfma_f32_16x16x32_bf16(k10, qf0, s1, 0, 0, 0);
    s1 = __builtin_amdgcn_mfma_f32_16x16x32_bf16(k11, qf1, s1, 0, 0, 0);

    int qpos = g*16 + l15;
    int kb0 = kt*32 + lg*4;
    float sv[2][4];
    #pragma unroll
    for (int r = 0; r < 4; ++r) {
      sv[0][r] = (kb0 + r      <= qpos) ? s0[r] : -1e30f;
      sv[1][r] = (kb0 + 16 + r <= qpos) ? s1[r] : -1e30f;
    }

    // online softmax over 32 keys (keys split: kb in-reg, lg cross-lane)
    float tmax = sv[0][0];
    #pragma unroll
    for (int r = 1; r < 4; ++r) tmax = fmaxf(tmax, sv[0][r]);
    #pragma unroll
    for (int r = 0; r < 4; ++r) tmax = fmaxf(tmax, sv[1][r]);
    tmax = fmaxf(tmax, __shfl_xor(tmax, 16));
    tmax = fmaxf(tmax, __shfl_xor(tmax, 32));
    float mn = fmaxf(m, tmax);
    float fac = __expf(m - mn);
    m = mn;
    float p[2][4];
    float rsum = 0.f;
    #pragma unroll
    for (int kb = 0; kb < 2; ++kb)
      #pragma unroll
      for (int r = 0; r < 4; ++r) { p[kb][r] = __expf(sv[kb][r] - mn); rsum += p[kb][r]; }
    rsum += __shfl_xor(rsum, 16);
    rsum += __shfl_xor(rsum, 32);
    lsum = lsum * fac + rsum;

    // P write: packed b64, slot-swizzled [q=l15][key]
    #pragma unroll
    for (int kb = 0; kb < 2; ++kb) {
      bf16x4 pk;
      pk[0] = (__bf16)p[kb][0]; pk[1] = (__bf16)p[kb][1];
      pk[2] = (__bf16)p[kb][2]; pk[3] = (__bf16)p[kb][3];
      int slot = kb*2 + (lg >> 1);
      *(bf16x4*)&Pl[l15*32 + (((slot ^ (l15 & 3)) << 3) | ((lg & 1) << 2))] = pk;
    }

    // rescale O (q = lg*4+r lives in rows; fac is per q=l15 -> shuffle)
    float f0 = __shfl(fac, lg*4 + 0);
    float f1 = __shfl(fac, lg*4 + 1);
    float f2 = __shfl(fac, lg*4 + 2);
    float f3 = __shfl(fac, lg*4 + 3);
    #pragma unroll
    for (int hc = 0; hc < 4; ++hc) {
      o[hc][0] *= f0; o[hc][1] *= f1; o[hc][2] *= f2; o[hc][3] *= f3;
    }

    // O += P @ V
    bf16x8 pa = *(const bf16x8*)&Pl[l15*32 + ((lg ^ (l15 & 3)) << 3)];
    #pragma unroll
    for (int hc = 0; hc < 4; ++hc) {
      int hd = hc*16 + l15;
      bf16x8 vf = *(const bf16x8*)&Vt[hd*32 + ((lg ^ (hd & 3)) << 3)];
      o[hc] = __builtin_amdgcn_mfma_f32_16x16x32_bf16(pa, vf, o[hc], 0, 0, 0);
    }
  };

  bf16x8 a00,a01,a10,a11,av0,av1,av2,av3;
  bf16x8 b00,b01,b10,b11,bv0,bv1,bv2,bv3;
  kload(0, a00,a01,a10,a11, av0,av1,av2,av3);
  for (int kt = 0; kt < nt; ) {
    if (kt + 1 < nt) kload(kt+1, b00,b01,b10,b11, bv0,bv1,bv2,bv3);
    process(kt, a00,a01,a10,a11, av0,av1,av2,av3);
    ++kt; if (kt >= nt) break;
    if (kt + 1 < nt) kload(kt+1, a00,a01,a10,a11, av0,av1,av2,av3);
    process(kt, b00,b01,b10,b11, bv0,bv1,bv2,bv3);
    ++kt;
  }

  float li0 = 1.0f / __shfl(lsum, lg*4 + 0);
  float li1 = 1.0f / __shfl(lsum, lg*4 + 1);
  float li2 = 1.0f / __shfl(lsum, lg*4 + 2);
  float li3 = 1.0f / __shfl(lsum, lg*4 + 3);
  #pragma unroll
  for (int hc = 0; hc < 4; ++hc) {
    size_t base = (size_t)(b*TT + g*16 + lg*4) * DD + h*HDD + hc*16 + l15;
    y[base]          = (__bf16)(o[hc][0] * li0);
    y[base + DD]     = (__bf16)(o[hc][1] * li1);
    y[base + 2*DD]   = (__bf16)(o[hc][2] * li2);
    y[base + 3*DD]   = (__bf16)(o[hc][3] * li3);
  }
}

extern "C" void kernel_launch(void* const* d_in, const int* in_sizes, int n_in,
                              void* d_out, int out_size, void* d_ws, size_t ws_size,
                              hipStream_t stream) {
  const int*   idx    = (const int*)d_in[0];
  const float* clip   = (const float*)d_in[1];
  const float* tok0   = (const float*)d_in[2];
  const float* tok1   = (const float*)d_in[3];
  const float* cond_w = (const float*)d_in[4];
  const float* cond_b = (const float*)d_in[5];
  const float* pos    = (const float*)d_in[6];
  const float* ln1_g  = (const float*)d_in[7];
  const float* ln1_b  = (const float*)d_in[8];
  const float* wq     = (const float*)d_in[9];
  const float* bq     = (const float*)d_in[10];
  const float* wk     = (const float*)d_in[11];
  const float* bk     = (const float*)d_in[12];
  const float* wv     = (const float*)d_in[13];
  const float* bv     = (const float*)d_in[14];
  const float* wo     = (const float*)d_in[15];
  const float* bo     = (const float*)d_in[16];
  const float* ln2_g  = (const float*)d_in[17];
  const float* ln2_b  = (const float*)d_in[18];
  const float* w1     = (const float*)d_in[19];
  const float* b1     = (const float*)d_in[20];
  const float* w2     = (const float*)d_in[21];
  const float* b2     = (const float*)d_in[22];

  float* x = (float*)d_out;
  char* wsb = (char*)d_ws;
  __bf16* wbuf = (__bf16*)wsb;                       // 6,291,456 B: [wq^T wk^T wv^T wo^T w1^T w2^T] bf16
  __bf16* h    = (__bf16*)(wsb + 6291456);           // 4 MB
  __bf16* qkv  = (__bf16*)(wsb + 10485760);          // 12 MB (4096 x 1536)
  __bf16* yb   = (__bf16*)(wsb + 23068672);          // 4 MB  (ends 27,262,976)
  __bf16* ffn  = qkv;                                // 16 MB alias (qkv+yb dead by then)

  embed_kernel<<<dim3(NTOK), 512, 0, stream>>>(idx, clip, tok0, tok1, cond_w, cond_b, pos, x);

  for (int i = 0; i < LL; ++i) {
    prep_kernel<<<dim3(3072), 256, 0, stream>>>(
        wq + (size_t)i*262144, wk + (size_t)i*262144, wv + (size_t)i*262144,
        wo + (size_t)i*262144, w1 + (size_t)i*1048576, w2 + (size_t)i*1048576, wbuf);

    ln_kernel<<<NTOK, 256, 0, stream>>>(x, ln1_g + i*DD, ln1_b + i*DD, h);

    mgemm<128,1,0,0,1><<<dim3(12, 32), 256, 0, stream>>>(
        h, wbuf, bq + i*DD, bk + i*DD, bv + i*DD, nullptr, nullptr, qkv, NTOK, 1536, 512);

    attn_kernel<<<dim3(256), 512, 0, stream>>>(qkv, yb);

    mgemm<64,0,1,0,0><<<dim3(4, 64), 256, 0, stream>>>(
        yb, wbuf + 786432, bo + i*DD, bo + i*DD, bo + i*DD, x, x, nullptr, NTOK, 512, 512);

    ln_kernel<<<NTOK, 256, 0, stream>>>(x, ln2_g + i*DD, ln2_b + i*DD, h);

    mgemm<128,0,0,1,1><<<dim3(16, 32), 256, 0, stream>>>(
        h, wbuf + 1048576, b1 + (size_t)i*4*DD, nullptr, nullptr, nullptr, nullptr, ffn, NTOK, 4*DD, 512);

    mgemm<64,0,1,0,0><<<dim3(4, 64), 256, 0, stream>>>(
        ffn, wbuf + 2097152, b2 + i*DD, nullptr, nullptr, x, x, nullptr, NTOK, 512, 2048);
  }
}

// Round 4
// 765.138 us; speedup vs baseline: 3.8543x; 1.0217x over previous
//
#include <hip/hip_runtime.h>
#include <math.h>

#define BB 2
#define TT 2048
#define DD 512
#define LL 4
#define HH 8
#define HDD 64
#define SEMN 50
#define CLIPN 512
#define NTOK (BB*TT)   // 4096
#define QS 1024        // qkv buffer row stride (Q|K only; V goes transposed)
#define VST 2056       // vt key-stride (2048 + 8, breaks 4KB aliasing)

typedef __bf16 bf16x8 __attribute__((ext_vector_type(8)));
typedef __bf16 bf16x4 __attribute__((ext_vector_type(4)));
typedef float  f32x4  __attribute__((ext_vector_type(4)));

#if __has_builtin(__builtin_amdgcn_global_load_lds)
#define USE_GLL 1
#endif

__device__ __forceinline__ void gll16(const __bf16* g, __bf16* l) {
#ifdef USE_GLL
  __builtin_amdgcn_global_load_lds((const __attribute__((address_space(1))) void*)g,
                                   (__attribute__((address_space(3))) void*)l, 16, 0, 0);
#endif
}

// ---------------- embedding + cond matvec + pos (fp32 out) ----------------
__global__ void embed_kernel(const int* __restrict__ idx, const float* __restrict__ clip,
                             const float* __restrict__ tok0, const float* __restrict__ tok1,
                             const float* __restrict__ cw, const float* __restrict__ cb,
                             const float* __restrict__ pos, float* __restrict__ x) {
  int row = blockIdx.x;
  int b = row / TT, t = row % TT;
  int d = threadIdx.x;
  float e;
  if (t == 0) {
    float acc = cb[d];
    for (int c = 0; c < CLIPN; ++c) acc = fmaf(clip[b*CLIPN + c], cw[c*DD + d], acc);
    e = acc;
  } else {
    int tok = idx[b*(TT-1) + (t-1)];
    e = (t <= SEMN) ? tok0[(size_t)tok*DD + d] : tok1[(size_t)tok*DD + d];
  }
  x[(size_t)row*DD + d] = e + pos[(size_t)t*DD + d];
}

// ---------------- layernorm: fp32 in -> bf16 out ----------------
__global__ __launch_bounds__(256) void ln_kernel(const float* __restrict__ x,
                                                 const float* __restrict__ g,
                                                 const float* __restrict__ bta,
                                                 __bf16* __restrict__ out) {
  int row = blockIdx.x;
  int tid = threadIdx.x;
  const float* xr = x + (size_t)row * DD;
  float v0 = xr[tid], v1 = xr[tid + 256];
  __shared__ float red[4];
  float s = v0 + v1;
  #pragma unroll
  for (int off = 32; off > 0; off >>= 1) s += __shfl_down(s, off);
  if ((tid & 63) == 0) red[tid >> 6] = s;
  __syncthreads();
  float mean = (red[0] + red[1] + red[2] + red[3]) * (1.0f / DD);
  float d0 = v0 - mean, d1 = v1 - mean;
  float sv = d0*d0 + d1*d1;
  #pragma unroll
  for (int off = 32; off > 0; off >>= 1) sv += __shfl_down(sv, off);
  __syncthreads();
  if ((tid & 63) == 0) red[tid >> 6] = sv;
  __syncthreads();
  float var = (red[0] + red[1] + red[2] + red[3]) * (1.0f / DD);
  float r = rsqrtf(var + 1e-5f);
  out[(size_t)row*DD + tid]       = (__bf16)(d0 * r * g[tid]       + bta[tid]);
  out[(size_t)row*DD + tid + 256] = (__bf16)(d1 * r * g[tid + 256] + bta[tid + 256]);
}

// ---------------- per-layer weight transpose+convert: [K,N] f32 -> [N,K] bf16 ----------------
__global__ __launch_bounds__(256) void prep_kernel(
    const float* __restrict__ wq, const float* __restrict__ wk,
    const float* __restrict__ wv, const float* __restrict__ wo,
    const float* __restrict__ w1, const float* __restrict__ w2,
    __bf16* __restrict__ wbuf) {
  __shared__ float tile[32][33];
  int id = blockIdx.x;
  const float* src; __bf16* dst; int K, N, t;
  if (id < 1024) {
    int m = id >> 8; t = id & 255;
    src = (m==0) ? wq : (m==1) ? wk : (m==2) ? wv : wo;
    dst = wbuf + (size_t)m * 262144; K = 512; N = 512;
  } else if (id < 2048) {
    t = id - 1024; src = w1; dst = wbuf + 1048576; K = 512; N = 2048;
  } else {
    t = id - 2048; src = w2; dst = wbuf + 2097152; K = 2048; N = 512;
  }
  int nsh = (N == 2048) ? 6 : 4;
  int tk = t >> nsh, tn = t & ((1 << nsh) - 1);
  int k0 = tk << 5, n0 = tn << 5;
  int tid = threadIdx.x;
  int r = tid >> 3, c = (tid & 7) << 2;
  float4 v = *(const float4*)&src[(size_t)(k0 + r)*N + n0 + c];
  tile[r][c+0] = v.x; tile[r][c+1] = v.y; tile[r][c+2] = v.z; tile[r][c+3] = v.w;
  __syncthreads();
  bf16x4 o;
  o[0] = (__bf16)tile[c+0][r];
  o[1] = (__bf16)tile[c+1][r];
  o[2] = (__bf16)tile[c+2][r];
  o[3] = (__bf16)tile[c+3][r];
  *(bf16x4*)&dst[(size_t)(n0 + r)*K + k0 + c] = o;
}

// ---------------- bf16 MFMA GEMM: C[M,N] = A[M,K] @ Bt[N,K]^T ----------------
// TM in {128,64}; TN = 128. QKV3: 3-way bias + V-cols written transposed to vtOut.
template<int TM, int QKV3, int RES, int GEL, int OB>
__global__ __launch_bounds__(256) void mgemm(
    const __bf16* __restrict__ A, const __bf16* __restrict__ Bt,
    const float* __restrict__ b0, const float* __restrict__ b1p, const float* __restrict__ b2p,
    const float* __restrict__ res, float* __restrict__ outF, __bf16* __restrict__ outB,
    __bf16* __restrict__ vtOut, int M, int N, int K, int ldo) {
  __shared__ __bf16 As[TM*32];
  __shared__ __bf16 Bs[128*32];
  int tid = threadIdx.x, wave = tid >> 6, l = tid & 63;
  int l15 = l & 15, lg = l >> 4;
  int m0 = blockIdx.y * TM, n0 = blockIdx.x << 7;
  constexpr int FM = 4;
  constexpr int FN = (TM == 128) ? 4 : 2;
  int wr = (TM == 128) ? (wave >> 1) : 0;
  int wc = (TM == 128) ? (wave & 1) : wave;

  f32x4 acc[FM][FN] = {};

  for (int k0 = 0; k0 < K; k0 += 32) {
#ifdef USE_GLL
    __syncthreads();    // previous tile consumed
    #pragma unroll
    for (int c = wave; c < TM/16; c += 4) {
      int row = c*16 + (l >> 2);
      int lslot = (l & 3) ^ ((row >> 1) & 3);
      gll16(A + (size_t)(m0+row)*K + k0 + lslot*8, &As[c*512]);
    }
    #pragma unroll
    for (int c = wave; c < 8; c += 4) {
      int row = c*16 + (l >> 2);
      int lslot = (l & 3) ^ ((row >> 1) & 3);
      gll16(Bt + (size_t)(n0+row)*K + k0 + lslot*8, &Bs[c*512]);
    }
    asm volatile("s_waitcnt vmcnt(0)" ::: "memory");
    __syncthreads();
#else
    bf16x8 ar[TM/64 > 0 ? TM/64 : 1], br[2];
    #pragma unroll
    for (int c = 0; c < TM/64; ++c) {
      int idx = tid + c*256;
      int row = idx >> 2;
      int lslot = (idx & 3) ^ ((row >> 1) & 3);
      ar[c] = *(const bf16x8*)(A + (size_t)(m0+row)*K + k0 + lslot*8);
    }
    #pragma unroll
    for (int c = 0; c < 2; ++c) {
      int idx = tid + c*256;
      int row = idx >> 2;
      int lslot = (idx & 3) ^ ((row >> 1) & 3);
      br[c] = *(const bf16x8*)(Bt + (size_t)(n0+row)*K + k0 + lslot*8);
    }
    __syncthreads();
    #pragma unroll
    for (int c = 0; c < TM/64; ++c) {
      int idx = tid + c*256;
      *(bf16x8*)&As[(idx >> 2)*32 + (idx & 3)*8] = ar[c];
    }
    #pragma unroll
    for (int c = 0; c < 2; ++c) {
      int idx = tid + c*256;
      *(bf16x8*)&Bs[(idx >> 2)*32 + (idx & 3)*8] = br[c];
    }
    __syncthreads();
#endif
    bf16x8 af[FM], bfr[FN];
    #pragma unroll
    for (int mi = 0; mi < FM; ++mi) {
      int row = (wr << 6) + (mi << 4) + l15;
      int ks = lg ^ ((row >> 1) & 3);
      af[mi] = *(const bf16x8*)&As[row*32 + (ks << 3)];
    }
    #pragma unroll
    for (int ni = 0; ni < FN; ++ni) {
      int row = wc*(FN*16) + (ni << 4) + l15;
      int ks = lg ^ ((row >> 1) & 3);
      bfr[ni] = *(const bf16x8*)&Bs[row*32 + (ks << 3)];
    }
    #pragma unroll
    for (int mi = 0; mi < FM; ++mi)
      #pragma unroll
      for (int ni = 0; ni < FN; ++ni)
        acc[mi][ni] = __builtin_amdgcn_mfma_f32_16x16x32_bf16(af[mi], bfr[ni], acc[mi][ni], 0, 0, 0);
  }

  #pragma unroll
  for (int mi = 0; mi < FM; ++mi) {
    #pragma unroll
    for (int ni = 0; ni < FN; ++ni) {
      int col = n0 + wc*(FN*16) + (ni << 4) + l15;
      float bs;
      if (QKV3) bs = (col < 512) ? b0[col] : (col < 1024) ? b1p[col-512] : b2p[col-1024];
      else bs = b0[col];
      int row0 = m0 + (wr << 6) + (mi << 4) + (lg << 2);
      if (QKV3 && col >= 1024) {
        // V columns: write transposed vt[bh][hd][key], key = token index
        int hdg = col - 1024;
        bf16x4 pk;
        #pragma unroll
        for (int r = 0; r < 4; ++r) pk[r] = (__bf16)(acc[mi][ni][r] + bs);
        size_t vrow = (size_t)(((row0 >> 11)*8 + (hdg >> 6))*64 + (hdg & 63));
        *(bf16x4*)&vtOut[vrow*VST + (row0 & 2047)] = pk;
      } else {
        #pragma unroll
        for (int r = 0; r < 4; ++r) {
          int row = row0 + r;
          float v = acc[mi][ni][r] + bs;
          if (RES) v += res[(size_t)row*ldo + col];
          if (GEL) v = 0.5f * v * (1.0f + erff(v * 0.70710678118654752f));
          if (OB) outB[(size_t)row*ldo + col] = (__bf16)v;
          else    outF[(size_t)row*ldo + col] = v;
        }
      }
    }
  }
}

// ---------------- barrier-free flash attention: 1 wave = (b,h,16 q-rows), KB=32 ----------------
// swapped QK^T: S^T = mfma(A=K, B=Q). K and V^T both direct global->reg (L2-resident).
// Only P round-trips through wave-private LDS (XOR-swizzled 16B slots).
__global__ __launch_bounds__(512) void attn_kernel(const __bf16* __restrict__ qkv,
                                                   const __bf16* __restrict__ vt,
                                                   __bf16* __restrict__ y) {
  __shared__ __bf16 Pall[8][512];   // per wave [16 q][32 key]
  int tid = threadIdx.x, wave = tid >> 6, l = tid & 63;
  int l15 = l & 15, lg = l >> 4;
  __bf16* Pl = Pall[wave];

  int wid = blockIdx.x * 8 + wave;     // 0..2047, longest-first
  int g  = 127 - (wid >> 4);           // q-group (16 rows) within (b,h)
  int bh = wid & 15;
  int b = bh >> 3, h = bh & 7;

  const __bf16* qp = qkv + (size_t)(b*TT)*QS + h*HDD;
  const __bf16* kp = qp + 512;
  const __bf16* vtp = vt + ((size_t)bh*64 + l15)*VST + lg*8;
  const __bf16* kbase = kp + (size_t)l15*QS + lg*8;

  // Q B-fragment (col=q=l15, k=hd=lg*8+e), pre-scaled by 1/sqrt(64)
  bf16x8 qf0, qf1;
  {
    size_t qr = (size_t)(g*16 + l15) * QS + lg*8;
    bf16x8 t0 = *(const bf16x8*)(qp + qr);
    bf16x8 t1 = *(const bf16x8*)(qp + qr + 32);
    #pragma unroll
    for (int e = 0; e < 8; ++e) {
      qf0[e] = (__bf16)((float)t0[e] * 0.125f);
      qf1[e] = (__bf16)((float)t1[e] * 0.125f);
    }
  }

  f32x4 o[4] = {};
  float m = -1e30f, lsum = 0.f;
  int qpos = g*16 + l15;
  int nt = (16*g + 47) >> 5;

  auto kload = [&](int kt, bf16x8& k00, bf16x8& k01, bf16x8& k10, bf16x8& k11,
                   bf16x8& v0, bf16x8& v1, bf16x8& v2, bf16x8& v3) {
    const __bf16* kr = kbase + (size_t)kt*32*QS;
    k00 = *(const bf16x8*)(kr);
    k01 = *(const bf16x8*)(kr + 32);
    k10 = *(const bf16x8*)(kr + 16*QS);
    k11 = *(const bf16x8*)(kr + 16*QS + 32);
    const __bf16* vr = vtp + kt*32;
    v0 = *(const bf16x8*)(vr);
    v1 = *(const bf16x8*)(vr + 16*VST);
    v2 = *(const bf16x8*)(vr + 32*VST);
    v3 = *(const bf16x8*)(vr + 48*VST);
  };

  auto process = [&](int kt, bf16x8 k00, bf16x8 k01, bf16x8 k10, bf16x8 k11,
                     bf16x8 v0, bf16x8 v1, bf16x8 v2, bf16x8 v3) {
    // S^T = K @ Q^T : rows=key (kb*16+lg*4+r), cols=q (l15)
    f32x4 s0 = {}, s1 = {};
    s0 = __builtin_amdgcn_mfma_f32_16x16x32_bf16(k00, qf0, s0, 0, 0, 0);
    s0 = __builtin_amdgcn_mfma_f32_16x16x32_bf16(k01, qf1, s0, 0, 0, 0);
    s1 = __builtin_amdgcn_mfma_f32_16x16x32_bf16(k10, qf0, s1, 0, 0, 0);
    s1 = __builtin_amdgcn_mfma_f32_16x16x32_bf16(k11, qf1, s1, 0, 0, 0);

    int kb0 = kt*32 + lg*4;
    float sv0[4], sv1[4];
    #pragma unroll
    for (int r = 0; r < 4; ++r) {
      sv0[r] = (kb0 + r      <= qpos) ? s0[r] : -1e30f;
      sv1[r] = (kb0 + 16 + r <= qpos) ? s1[r] : -1e30f;
    }

    // tile max per q (in-lane over 8 keys, cross-lane over lg)
    float tmax = fmaxf(fmaxf(fmaxf(sv0[0],sv0[1]), fmaxf(sv0[2],sv0[3])),
                       fmaxf(fmaxf(sv1[0],sv1[1]), fmaxf(sv1[2],sv1[3])));
    tmax = fmaxf(tmax, __shfl_xor(tmax, 16));
    tmax = fmaxf(tmax, __shfl_xor(tmax, 32));

    // defer-max (T13, THR=8): skip O-rescale when max growth small
    if (!__all(tmax - m <= 8.0f)) {
      float mn = fmaxf(m, tmax);
      float fac = __expf(m - mn);
      m = mn;
      lsum *= fac;
      float f0 = __shfl(fac, lg*4+0), f1 = __shfl(fac, lg*4+1);
      float f2 = __shfl(fac, lg*4+2), f3 = __shfl(fac, lg*4+3);
      #pragma unroll
      for (int hc = 0; hc < 4; ++hc) {
        o[hc][0] *= f0; o[hc][1] *= f1; o[hc][2] *= f2; o[hc][3] *= f3;
      }
    }

    float rsum = 0.f;
    bf16x4 pk0, pk1;
    #pragma unroll
    for (int r = 0; r < 4; ++r) {
      float p0 = __expf(sv0[r] - m);
      float p1 = __expf(sv1[r] - m);
      rsum += p0 + p1;
      pk0[r] = (__bf16)p0;
      pk1[r] = (__bf16)p1;
    }
    rsum += __shfl_xor(rsum, 16);
    rsum += __shfl_xor(rsum, 32);
    lsum += rsum;

    // P^T -> P via wave-private LDS, 16B-slot XOR swizzle
    int ws0 = (((lg >> 1) + 0) ^ (l15 & 3));
    int ws1 = (((lg >> 1) + 2) ^ (l15 & 3));
    *(bf16x4*)&Pl[l15*32 + ws0*8 + (lg & 1)*4] = pk0;
    *(bf16x4*)&Pl[l15*32 + ws1*8 + (lg & 1)*4] = pk1;
    asm volatile("s_waitcnt lgkmcnt(0)" ::: "memory");
    __builtin_amdgcn_sched_barrier(0);
    bf16x8 pa = *(const bf16x8*)&Pl[l15*32 + (lg ^ (l15 & 3))*8];

    // O += P @ V : A=P[q=l15][k=key], B=V^T (k=key, col=hd=hc*16+l15)
    o[0] = __builtin_amdgcn_mfma_f32_16x16x32_bf16(pa, v0, o[0], 0, 0, 0);
    o[1] = __builtin_amdgcn_mfma_f32_16x16x32_bf16(pa, v1, o[1], 0, 0, 0);
    o[2] = __builtin_amdgcn_mfma_f32_16x16x32_bf16(pa, v2, o[2], 0, 0, 0);
    o[3] = __builtin_amdgcn_mfma_f32_16x16x32_bf16(pa, v3, o[3], 0, 0, 0);
  };

  bf16x8 a00,a01,a10,a11,av0,av1,av2,av3;
  bf16x8 b00,b01,b10,b11,bv0,bv1,bv2,bv3;
  kload(0, a00,a01,a10,a11, av0,av1,av2,av3);
  for (int kt = 0; kt < nt; ) {
    if (kt + 1 < nt) kload(kt+1, b00,b01,b10,b11, bv0,bv1,bv2,bv3);
    process(kt, a00,a01,a10,a11, av0,av1,av2,av3);
    ++kt; if (kt >= nt) break;
    if (kt + 1 < nt) kload(kt+1, a00,a01,a10,a11, av0,av1,av2,av3);
    process(kt, b00,b01,b10,b11, bv0,bv1,bv2,bv3);
    ++kt;
  }

  float li0 = 1.0f / __shfl(lsum, lg*4 + 0);
  float li1 = 1.0f / __shfl(lsum, lg*4 + 1);
  float li2 = 1.0f / __shfl(lsum, lg*4 + 2);
  float li3 = 1.0f / __shfl(lsum, lg*4 + 3);
  #pragma unroll
  for (int hc = 0; hc < 4; ++hc) {
    size_t base = (size_t)(b*TT + g*16 + lg*4) * DD + h*HDD + hc*16 + l15;
    y[base]        = (__bf16)(o[hc][0] * li0);
    y[base + DD]   = (__bf16)(o[hc][1] * li1);
    y[base + 2*DD] = (__bf16)(o[hc][2] * li2);
    y[base + 3*DD] = (__bf16)(o[hc][3] * li3);
  }
}

extern "C" void kernel_launch(void* const* d_in, const int* in_sizes, int n_in,
                              void* d_out, int out_size, void* d_ws, size_t ws_size,
                              hipStream_t stream) {
  const int*   idx    = (const int*)d_in[0];
  const float* clip   = (const float*)d_in[1];
  const float* tok0   = (const float*)d_in[2];
  const float* tok1   = (const float*)d_in[3];
  const float* cond_w = (const float*)d_in[4];
  const float* cond_b = (const float*)d_in[5];
  const float* pos    = (const float*)d_in[6];
  const float* ln1_g  = (const float*)d_in[7];
  const float* ln1_b  = (const float*)d_in[8];
  const float* wq     = (const float*)d_in[9];
  const float* bq     = (const float*)d_in[10];
  const float* wk     = (const float*)d_in[11];
  const float* bk     = (const float*)d_in[12];
  const float* wv     = (const float*)d_in[13];
  const float* bv     = (const float*)d_in[14];
  const float* wo     = (const float*)d_in[15];
  const float* bo     = (const float*)d_in[16];
  const float* ln2_g  = (const float*)d_in[17];
  const float* ln2_b  = (const float*)d_in[18];
  const float* w1     = (const float*)d_in[19];
  const float* b1     = (const float*)d_in[20];
  const float* w2     = (const float*)d_in[21];
  const float* b2     = (const float*)d_in[22];

  float* x = (float*)d_out;
  char* wsb = (char*)d_ws;
  __bf16* wbuf = (__bf16*)wsb;                       // 6,291,456 B: [wq^T wk^T wv^T wo^T w1^T w2^T] bf16
  __bf16* h    = (__bf16*)(wsb + 6291456);           // 4 MB ln out
  __bf16* qkv  = (__bf16*)(wsb + 10485760);          // 8 MB (4096 x 1024: Q|K)
  __bf16* yb   = (__bf16*)(wsb + 23068672);          // 4 MB attn out (ends 27,262,976)
  __bf16* ffn  = qkv;                                // 16 MB alias (qkv..yb dead by then)
  __bf16* vt   = (__bf16*)(wsb + 27262976);          // 4,210,688 B: [16 bh][64 hd][2056]

  embed_kernel<<<dim3(NTOK), 512, 0, stream>>>(idx, clip, tok0, tok1, cond_w, cond_b, pos, x);

  for (int i = 0; i < LL; ++i) {
    prep_kernel<<<dim3(3072), 256, 0, stream>>>(
        wq + (size_t)i*262144, wk + (size_t)i*262144, wv + (size_t)i*262144,
        wo + (size_t)i*262144, w1 + (size_t)i*1048576, w2 + (size_t)i*1048576, wbuf);

    ln_kernel<<<NTOK, 256, 0, stream>>>(x, ln1_g + i*DD, ln1_b + i*DD, h);

    mgemm<128,1,0,0,1><<<dim3(12, 32), 256, 0, stream>>>(
        h, wbuf, bq + i*DD, bk + i*DD, bv + i*DD, nullptr, nullptr, qkv, vt, NTOK, 1536, 512, 1024);

    attn_kernel<<<dim3(256), 512, 0, stream>>>(qkv, vt, yb);

    mgemm<64,0,1,0,0><<<dim3(4, 64), 256, 0, stream>>>(
        yb, wbuf + 786432, bo + i*DD, nullptr, nullptr, x, x, nullptr, nullptr, NTOK, 512, 512, 512);

    ln_kernel<<<NTOK, 256, 0, stream>>>(x, ln2_g + i*DD, ln2_b + i*DD, h);

    mgemm<128,0,0,1,1><<<dim3(16, 32), 256, 0, stream>>>(
        h, wbuf + 1048576, b1 + (size_t)i*4*DD, nullptr, nullptr, nullptr, nullptr, ffn, nullptr, NTOK, 4*DD, 512, 2048);

    mgemm<64,0,1,0,0><<<dim3(4, 64), 256, 0, stream>>>(
        ffn, wbuf + 2097152, b2 + i*DD, nullptr, nullptr, x, x, nullptr, nullptr, NTOK, 512, 2048, 512);
  }
}

// Round 5
// 640.144 us; speedup vs baseline: 4.6068x; 1.1953x over previous
//
#include <hip/hip_runtime.h>
#include <math.h>

#define BB 2
#define TT 2048
#define DD 512
#define LL 4
#define HH 8
#define HDD 64
#define SEMN 50
#define CLIPN 512
#define NTOK (BB*TT)   // 4096
#define QS 1024        // qkv buffer row stride (Q|K only; V goes transposed)
#define VST 2056       // vt key-stride (2048 + 8, breaks 4KB aliasing)

typedef __bf16 bf16x8 __attribute__((ext_vector_type(8)));
typedef __bf16 bf16x4 __attribute__((ext_vector_type(4)));
typedef float  f32x4  __attribute__((ext_vector_type(4)));

#if __has_builtin(__builtin_amdgcn_global_load_lds)
#define USE_GLL 1
#endif

__device__ __forceinline__ void gll16(const __bf16* g, __bf16* l) {
#ifdef USE_GLL
  __builtin_amdgcn_global_load_lds((const __attribute__((address_space(1))) void*)g,
                                   (__attribute__((address_space(3))) void*)l, 16, 0, 0);
#endif
}

// ---------------- embedding + cond matvec + pos (fp32 out) ----------------
__global__ void embed_kernel(const int* __restrict__ idx, const float* __restrict__ clip,
                             const float* __restrict__ tok0, const float* __restrict__ tok1,
                             const float* __restrict__ cw, const float* __restrict__ cb,
                             const float* __restrict__ pos, float* __restrict__ x) {
  int row = blockIdx.x;
  int b = row / TT, t = row % TT;
  int d = threadIdx.x;
  float e;
  if (t == 0) {
    float acc = cb[d];
    for (int c = 0; c < CLIPN; ++c) acc = fmaf(clip[b*CLIPN + c], cw[c*DD + d], acc);
    e = acc;
  } else {
    int tok = idx[b*(TT-1) + (t-1)];
    e = (t <= SEMN) ? tok0[(size_t)tok*DD + d] : tok1[(size_t)tok*DD + d];
  }
  x[(size_t)row*DD + d] = e + pos[(size_t)t*DD + d];
}

// ---------------- layernorm: fp32 in -> bf16 out ----------------
__global__ __launch_bounds__(256) void ln_kernel(const float* __restrict__ x,
                                                 const float* __restrict__ g,
                                                 const float* __restrict__ bta,
                                                 __bf16* __restrict__ out) {
  int row = blockIdx.x;
  int tid = threadIdx.x;
  const float* xr = x + (size_t)row * DD;
  float v0 = xr[tid], v1 = xr[tid + 256];
  __shared__ float red[4];
  float s = v0 + v1;
  #pragma unroll
  for (int off = 32; off > 0; off >>= 1) s += __shfl_down(s, off);
  if ((tid & 63) == 0) red[tid >> 6] = s;
  __syncthreads();
  float mean = (red[0] + red[1] + red[2] + red[3]) * (1.0f / DD);
  float d0 = v0 - mean, d1 = v1 - mean;
  float sv = d0*d0 + d1*d1;
  #pragma unroll
  for (int off = 32; off > 0; off >>= 1) sv += __shfl_down(sv, off);
  __syncthreads();
  if ((tid & 63) == 0) red[tid >> 6] = sv;
  __syncthreads();
  float var = (red[0] + red[1] + red[2] + red[3]) * (1.0f / DD);
  float r = rsqrtf(var + 1e-5f);
  out[(size_t)row*DD + tid]       = (__bf16)(d0 * r * g[tid]       + bta[tid]);
  out[(size_t)row*DD + tid + 256] = (__bf16)(d1 * r * g[tid + 256] + bta[tid + 256]);
}

// ---------------- per-layer weight transpose+convert: [K,N] f32 -> [N,K] bf16 ----------------
__global__ __launch_bounds__(256) void prep_kernel(
    const float* __restrict__ wq, const float* __restrict__ wk,
    const float* __restrict__ wv, const float* __restrict__ wo,
    const float* __restrict__ w1, const float* __restrict__ w2,
    __bf16* __restrict__ wbuf) {
  __shared__ float tile[32][33];
  int id = blockIdx.x;
  const float* src; __bf16* dst; int K, N, t;
  if (id < 1024) {
    int m = id >> 8; t = id & 255;
    src = (m==0) ? wq : (m==1) ? wk : (m==2) ? wv : wo;
    dst = wbuf + (size_t)m * 262144; K = 512; N = 512;
  } else if (id < 2048) {
    t = id - 1024; src = w1; dst = wbuf + 1048576; K = 512; N = 2048;
  } else {
    t = id - 2048; src = w2; dst = wbuf + 2097152; K = 2048; N = 512;
  }
  int nsh = (N == 2048) ? 6 : 4;
  int tk = t >> nsh, tn = t & ((1 << nsh) - 1);
  int k0 = tk << 5, n0 = tn << 5;
  int tid = threadIdx.x;
  int r = tid >> 3, c = (tid & 7) << 2;
  float4 v = *(const float4*)&src[(size_t)(k0 + r)*N + n0 + c];
  tile[r][c+0] = v.x; tile[r][c+1] = v.y; tile[r][c+2] = v.z; tile[r][c+3] = v.w;
  __syncthreads();
  bf16x4 o;
  o[0] = (__bf16)tile[c+0][r];
  o[1] = (__bf16)tile[c+1][r];
  o[2] = (__bf16)tile[c+2][r];
  o[3] = (__bf16)tile[c+3][r];
  *(bf16x4*)&dst[(size_t)(n0 + r)*K + k0 + c] = o;
}

// ---------------- bf16 MFMA GEMM: C[M,N] = A[M,K] @ Bt[N,K]^T ----------------
// TM in {128,64}; TN = 128. QKV3: 3-way bias + V-cols written transposed to vtOut.
template<int TM, int QKV3, int RES, int GEL, int OB>
__global__ __launch_bounds__(256) void mgemm(
    const __bf16* __restrict__ A, const __bf16* __restrict__ Bt,
    const float* __restrict__ b0, const float* __restrict__ b1p, const float* __restrict__ b2p,
    const float* __restrict__ res, float* __restrict__ outF, __bf16* __restrict__ outB,
    __bf16* __restrict__ vtOut, int M, int N, int K, int ldo) {
  __shared__ __bf16 As[TM*32];
  __shared__ __bf16 Bs[128*32];
  int tid = threadIdx.x, wave = tid >> 6, l = tid & 63;
  int l15 = l & 15, lg = l >> 4;
  int m0 = blockIdx.y * TM, n0 = blockIdx.x << 7;
  constexpr int FM = 4;
  constexpr int FN = (TM == 128) ? 4 : 2;
  int wr = (TM == 128) ? (wave >> 1) : 0;
  int wc = (TM == 128) ? (wave & 1) : wave;

  f32x4 acc[FM][FN] = {};

  for (int k0 = 0; k0 < K; k0 += 32) {
#ifdef USE_GLL
    __syncthreads();    // previous tile consumed
    #pragma unroll
    for (int c = wave; c < TM/16; c += 4) {
      int row = c*16 + (l >> 2);
      int lslot = (l & 3) ^ ((row >> 1) & 3);
      gll16(A + (size_t)(m0+row)*K + k0 + lslot*8, &As[c*512]);
    }
    #pragma unroll
    for (int c = wave; c < 8; c += 4) {
      int row = c*16 + (l >> 2);
      int lslot = (l & 3) ^ ((row >> 1) & 3);
      gll16(Bt + (size_t)(n0+row)*K + k0 + lslot*8, &Bs[c*512]);
    }
    asm volatile("s_waitcnt vmcnt(0)" ::: "memory");
    __syncthreads();
#else
    bf16x8 ar[TM/64 > 0 ? TM/64 : 1], br[2];
    #pragma unroll
    for (int c = 0; c < TM/64; ++c) {
      int idx = tid + c*256;
      int row = idx >> 2;
      int lslot = (idx & 3) ^ ((row >> 1) & 3);
      ar[c] = *(const bf16x8*)(A + (size_t)(m0+row)*K + k0 + lslot*8);
    }
    #pragma unroll
    for (int c = 0; c < 2; ++c) {
      int idx = tid + c*256;
      int row = idx >> 2;
      int lslot = (idx & 3) ^ ((row >> 1) & 3);
      br[c] = *(const bf16x8*)(Bt + (size_t)(n0+row)*K + k0 + lslot*8);
    }
    __syncthreads();
    #pragma unroll
    for (int c = 0; c < TM/64; ++c) {
      int idx = tid + c*256;
      *(bf16x8*)&As[(idx >> 2)*32 + (idx & 3)*8] = ar[c];
    }
    #pragma unroll
    for (int c = 0; c < 2; ++c) {
      int idx = tid + c*256;
      *(bf16x8*)&Bs[(idx >> 2)*32 + (idx & 3)*8] = br[c];
    }
    __syncthreads();
#endif
    bf16x8 af[FM], bfr[FN];
    #pragma unroll
    for (int mi = 0; mi < FM; ++mi) {
      int row = (wr << 6) + (mi << 4) + l15;
      int ks = lg ^ ((row >> 1) & 3);
      af[mi] = *(const bf16x8*)&As[row*32 + (ks << 3)];
    }
    #pragma unroll
    for (int ni = 0; ni < FN; ++ni) {
      int row = wc*(FN*16) + (ni << 4) + l15;
      int ks = lg ^ ((row >> 1) & 3);
      bfr[ni] = *(const bf16x8*)&Bs[row*32 + (ks << 3)];
    }
    #pragma unroll
    for (int mi = 0; mi < FM; ++mi)
      #pragma unroll
      for (int ni = 0; ni < FN; ++ni)
        acc[mi][ni] = __builtin_amdgcn_mfma_f32_16x16x32_bf16(af[mi], bfr[ni], acc[mi][ni], 0, 0, 0);
  }

  #pragma unroll
  for (int mi = 0; mi < FM; ++mi) {
    #pragma unroll
    for (int ni = 0; ni < FN; ++ni) {
      int col = n0 + wc*(FN*16) + (ni << 4) + l15;
      float bs;
      if (QKV3) bs = (col < 512) ? b0[col] : (col < 1024) ? b1p[col-512] : b2p[col-1024];
      else bs = b0[col];
      int row0 = m0 + (wr << 6) + (mi << 4) + (lg << 2);
      if (QKV3 && col >= 1024) {
        // V columns: write transposed vt[bh][hd][key], key = token index
        int hdg = col - 1024;
        bf16x4 pk;
        #pragma unroll
        for (int r = 0; r < 4; ++r) pk[r] = (__bf16)(acc[mi][ni][r] + bs);
        size_t vrow = (size_t)(((row0 >> 11)*8 + (hdg >> 6))*64 + (hdg & 63));
        *(bf16x4*)&vtOut[vrow*VST + (row0 & 2047)] = pk;
      } else {
        #pragma unroll
        for (int r = 0; r < 4; ++r) {
          int row = row0 + r;
          float v = acc[mi][ni][r] + bs;
          if (RES) v += res[(size_t)row*ldo + col];
          if (GEL) v = 0.5f * v * (1.0f + erff(v * 0.70710678118654752f));
          if (OB) outB[(size_t)row*ldo + col] = (__bf16)v;
          else    outF[(size_t)row*ldo + col] = v;
        }
      }
    }
  }
}

// ---------------- barrier-free flash attention: 1 wave PER BLOCK = (b,h,16 q-rows) ----------------
// swapped QK^T: S^T = mfma(A=K, B=Q). K and V^T direct global->reg (L2-resident).
// 64-thread blocks: HW scheduler load-balances 2048 independent waves (longest-first)
// and co-resides up to ~7 waves/SIMD (VGPR-limited) for latency hiding.
__global__ __launch_bounds__(64) void attn_kernel(const __bf16* __restrict__ qkv,
                                                  const __bf16* __restrict__ vt,
                                                  __bf16* __restrict__ y) {
  __shared__ __attribute__((aligned(16))) __bf16 Pl[16*40];  // [16 q][32 key], stride 40 (+2-way max banks)
  int l = threadIdx.x;
  int l15 = l & 15, lg = l >> 4;

  int wid = blockIdx.x;                // 0..2047, longest-first
  int g  = 127 - (wid >> 4);           // q-group (16 rows) within (b,h)
  int bh = wid & 15;
  int b = bh >> 3, h = bh & 7;

  const __bf16* qp = qkv + (size_t)(b*TT)*QS + h*HDD;
  const __bf16* kp = qp + 512;
  const __bf16* vtp = vt + ((size_t)bh*64 + l15)*VST + lg*8;
  const __bf16* kbase = kp + (size_t)l15*QS + lg*8;

  // Q B-fragment (col=q=l15, k=hd=lg*8+e), pre-scaled by 1/sqrt(64)
  bf16x8 qf0, qf1;
  {
    size_t qr = (size_t)(g*16 + l15) * QS + lg*8;
    bf16x8 t0 = *(const bf16x8*)(qp + qr);
    bf16x8 t1 = *(const bf16x8*)(qp + qr + 32);
    #pragma unroll
    for (int e = 0; e < 8; ++e) {
      qf0[e] = (__bf16)((float)t0[e] * 0.125f);
      qf1[e] = (__bf16)((float)t1[e] * 0.125f);
    }
  }

  f32x4 o[4] = {};
  float m = -1e30f, lsum = 0.f;
  int qpos = g*16 + l15;
  int nt = (16*g + 47) >> 5;

  auto kload = [&](int kt, bf16x8& k00, bf16x8& k01, bf16x8& k10, bf16x8& k11,
                   bf16x8& v0, bf16x8& v1, bf16x8& v2, bf16x8& v3) {
    const __bf16* kr = kbase + (size_t)kt*32*QS;
    k00 = *(const bf16x8*)(kr);
    k01 = *(const bf16x8*)(kr + 32);
    k10 = *(const bf16x8*)(kr + 16*QS);
    k11 = *(const bf16x8*)(kr + 16*QS + 32);
    const __bf16* vr = vtp + kt*32;
    v0 = *(const bf16x8*)(vr);
    v1 = *(const bf16x8*)(vr + 16*VST);
    v2 = *(const bf16x8*)(vr + 32*VST);
    v3 = *(const bf16x8*)(vr + 48*VST);
  };

  auto process = [&](int kt, bf16x8 k00, bf16x8 k01, bf16x8 k10, bf16x8 k11,
                     bf16x8 v0, bf16x8 v1, bf16x8 v2, bf16x8 v3) {
    // S^T = K @ Q^T : rows=key (kb*16+lg*4+r), cols=q (l15)
    f32x4 s0 = {}, s1 = {};
    s0 = __builtin_amdgcn_mfma_f32_16x16x32_bf16(k00, qf0, s0, 0, 0, 0);
    s0 = __builtin_amdgcn_mfma_f32_16x16x32_bf16(k01, qf1, s0, 0, 0, 0);
    s1 = __builtin_amdgcn_mfma_f32_16x16x32_bf16(k10, qf0, s1, 0, 0, 0);
    s1 = __builtin_amdgcn_mfma_f32_16x16x32_bf16(k11, qf1, s1, 0, 0, 0);

    int kb0 = kt*32 + lg*4;
    float sv0[4], sv1[4];
    #pragma unroll
    for (int r = 0; r < 4; ++r) {
      sv0[r] = (kb0 + r      <= qpos) ? s0[r] : -1e30f;
      sv1[r] = (kb0 + 16 + r <= qpos) ? s1[r] : -1e30f;
    }

    // tile max per q (in-lane over 8 keys, cross-lane over lg)
    float tmax = fmaxf(fmaxf(fmaxf(sv0[0],sv0[1]), fmaxf(sv0[2],sv0[3])),
                       fmaxf(fmaxf(sv1[0],sv1[1]), fmaxf(sv1[2],sv1[3])));
    tmax = fmaxf(tmax, __shfl_xor(tmax, 16));
    tmax = fmaxf(tmax, __shfl_xor(tmax, 32));

    // defer-max (T13, THR=8): skip O-rescale when max growth small
    if (!__all(tmax - m <= 8.0f)) {
      float mn = fmaxf(m, tmax);
      float fac = __expf(m - mn);
      m = mn;
      lsum *= fac;
      float f0 = __shfl(fac, lg*4+0), f1 = __shfl(fac, lg*4+1);
      float f2 = __shfl(fac, lg*4+2), f3 = __shfl(fac, lg*4+3);
      #pragma unroll
      for (int hc = 0; hc < 4; ++hc) {
        o[hc][0] *= f0; o[hc][1] *= f1; o[hc][2] *= f2; o[hc][3] *= f3;
      }
    }

    float rsum = 0.f;
    bf16x4 pk0, pk1;
    #pragma unroll
    for (int r = 0; r < 4; ++r) {
      float p0 = __expf(sv0[r] - m);
      float p1 = __expf(sv1[r] - m);
      rsum += p0 + p1;
      pk0[r] = (__bf16)p0;
      pk1[r] = (__bf16)p1;
    }
    rsum += __shfl_xor(rsum, 16);
    rsum += __shfl_xor(rsum, 32);
    lsum += rsum;

    // P^T -> P via wave-private LDS, 16B-slot XOR swizzle, row stride 40 elem (80B)
    int s0i = ((lg >> 1)     ) ^ (l15 & 3);
    int s1i = ((lg >> 1) + 2 ) ^ (l15 & 3);
    *(bf16x4*)&Pl[l15*40 + s0i*8 + (lg & 1)*4] = pk0;
    *(bf16x4*)&Pl[l15*40 + s1i*8 + (lg & 1)*4] = pk1;
    asm volatile("s_waitcnt lgkmcnt(0)" ::: "memory");
    __builtin_amdgcn_sched_barrier(0);
    bf16x8 pa = *(const bf16x8*)&Pl[l15*40 + ((lg ^ (l15 & 3))*8)];

    // O += P @ V : A=P[q=l15][k=key], B=V^T (k=key, col=hd=hc*16+l15)
    o[0] = __builtin_amdgcn_mfma_f32_16x16x32_bf16(pa, v0, o[0], 0, 0, 0);
    o[1] = __builtin_amdgcn_mfma_f32_16x16x32_bf16(pa, v1, o[1], 0, 0, 0);
    o[2] = __builtin_amdgcn_mfma_f32_16x16x32_bf16(pa, v2, o[2], 0, 0, 0);
    o[3] = __builtin_amdgcn_mfma_f32_16x16x32_bf16(pa, v3, o[3], 0, 0, 0);
  };

  bf16x8 a00,a01,a10,a11,av0,av1,av2,av3;
  bf16x8 b00,b01,b10,b11,bv0,bv1,bv2,bv3;
  kload(0, a00,a01,a10,a11, av0,av1,av2,av3);
  for (int kt = 0; kt < nt; ) {
    if (kt + 1 < nt) kload(kt+1, b00,b01,b10,b11, bv0,bv1,bv2,bv3);
    process(kt, a00,a01,a10,a11, av0,av1,av2,av3);
    ++kt; if (kt >= nt) break;
    if (kt + 1 < nt) kload(kt+1, a00,a01,a10,a11, av0,av1,av2,av3);
    process(kt, b00,b01,b10,b11, bv0,bv1,bv2,bv3);
    ++kt;
  }

  float li0 = 1.0f / __shfl(lsum, lg*4 + 0);
  float li1 = 1.0f / __shfl(lsum, lg*4 + 1);
  float li2 = 1.0f / __shfl(lsum, lg*4 + 2);
  float li3 = 1.0f / __shfl(lsum, lg*4 + 3);
  #pragma unroll
  for (int hc = 0; hc < 4; ++hc) {
    size_t base = (size_t)(b*TT + g*16 + lg*4) * DD + h*HDD + hc*16 + l15;
    y[base]        = (__bf16)(o[hc][0] * li0);
    y[base + DD]   = (__bf16)(o[hc][1] * li1);
    y[base + 2*DD] = (__bf16)(o[hc][2] * li2);
    y[base + 3*DD] = (__bf16)(o[hc][3] * li3);
  }
}

extern "C" void kernel_launch(void* const* d_in, const int* in_sizes, int n_in,
                              void* d_out, int out_size, void* d_ws, size_t ws_size,
                              hipStream_t stream) {
  const int*   idx    = (const int*)d_in[0];
  const float* clip   = (const float*)d_in[1];
  const float* tok0   = (const float*)d_in[2];
  const float* tok1   = (const float*)d_in[3];
  const float* cond_w = (const float*)d_in[4];
  const float* cond_b = (const float*)d_in[5];
  const float* pos    = (const float*)d_in[6];
  const float* ln1_g  = (const float*)d_in[7];
  const float* ln1_b  = (const float*)d_in[8];
  const float* wq     = (const float*)d_in[9];
  const float* bq     = (const float*)d_in[10];
  const float* wk     = (const float*)d_in[11];
  const float* bk     = (const float*)d_in[12];
  const float* wv     = (const float*)d_in[13];
  const float* bv     = (const float*)d_in[14];
  const float* wo     = (const float*)d_in[15];
  const float* bo     = (const float*)d_in[16];
  const float* ln2_g  = (const float*)d_in[17];
  const float* ln2_b  = (const float*)d_in[18];
  const float* w1     = (const float*)d_in[19];
  const float* b1     = (const float*)d_in[20];
  const float* w2     = (const float*)d_in[21];
  const float* b2     = (const float*)d_in[22];

  float* x = (float*)d_out;
  char* wsb = (char*)d_ws;
  __bf16* wbuf = (__bf16*)wsb;                       // 6,291,456 B: [wq^T wk^T wv^T wo^T w1^T w2^T] bf16
  __bf16* h    = (__bf16*)(wsb + 6291456);           // 4 MB ln out
  __bf16* qkv  = (__bf16*)(wsb + 10485760);          // 8 MB (4096 x 1024: Q|K)
  __bf16* yb   = (__bf16*)(wsb + 23068672);          // 4 MB attn out (ends 27,262,976)
  __bf16* ffn  = qkv;                                // 16 MB alias (qkv..yb dead by then)
  __bf16* vt   = (__bf16*)(wsb + 27262976);          // 4,210,688 B: [16 bh][64 hd][2056]

  embed_kernel<<<dim3(NTOK), 512, 0, stream>>>(idx, clip, tok0, tok1, cond_w, cond_b, pos, x);

  for (int i = 0; i < LL; ++i) {
    prep_kernel<<<dim3(3072), 256, 0, stream>>>(
        wq + (size_t)i*262144, wk + (size_t)i*262144, wv + (size_t)i*262144,
        wo + (size_t)i*262144, w1 + (size_t)i*1048576, w2 + (size_t)i*1048576, wbuf);

    ln_kernel<<<NTOK, 256, 0, stream>>>(x, ln1_g + i*DD, ln1_b + i*DD, h);

    mgemm<128,1,0,0,1><<<dim3(12, 32), 256, 0, stream>>>(
        h, wbuf, bq + i*DD, bk + i*DD, bv + i*DD, nullptr, nullptr, qkv, vt, NTOK, 1536, 512, 1024);

    attn_kernel<<<dim3(2048), 64, 0, stream>>>(qkv, vt, yb);

    mgemm<64,0,1,0,0><<<dim3(4, 64), 256, 0, stream>>>(
        yb, wbuf + 786432, bo + i*DD, nullptr, nullptr, x, x, nullptr, nullptr, NTOK, 512, 512, 512);

    ln_kernel<<<NTOK, 256, 0, stream>>>(x, ln2_g + i*DD, ln2_b + i*DD, h);

    mgemm<128,0,0,1,1><<<dim3(16, 32), 256, 0, stream>>>(
        h, wbuf + 1048576, b1 + (size_t)i*4*DD, nullptr, nullptr, nullptr, nullptr, ffn, nullptr, NTOK, 4*DD, 512, 2048);

    mgemm<64,0,1,0,0><<<dim3(4, 64), 256, 0, stream>>>(
        ffn, wbuf + 2097152, b2 + i*DD, nullptr, nullptr, x, x, nullptr, nullptr, NTOK, 512, 2048, 512);
  }
}

// Round 6
// 608.446 us; speedup vs baseline: 4.8468x; 1.0521x over previous
//
#include <hip/hip_runtime.h>
#include <math.h>

#define BB 2
#define TT 2048
#define DD 512
#define LL 4
#define HH 8
#define HDD 64
#define SEMN 50
#define CLIPN 512
#define NTOK (BB*TT)   // 4096
#define QS 1024        // qkv buffer row stride (Q|K only; V goes transposed)
#define VST 2056       // vt key-stride (2048 + 8, breaks 4KB aliasing)

typedef __bf16 bf16x8 __attribute__((ext_vector_type(8)));
typedef __bf16 bf16x4 __attribute__((ext_vector_type(4)));
typedef float  f32x4  __attribute__((ext_vector_type(4)));

#if __has_builtin(__builtin_amdgcn_global_load_lds)
#define USE_GLL 1
#endif

__device__ __forceinline__ void gll16(const __bf16* g, __bf16* l) {
#ifdef USE_GLL
  __builtin_amdgcn_global_load_lds((const __attribute__((address_space(1))) void*)g,
                                   (__attribute__((address_space(3))) void*)l, 16, 0, 0);
#endif
}

// ---------------- embedding + cond matvec + pos (fp32 out) ----------------
__global__ void embed_kernel(const int* __restrict__ idx, const float* __restrict__ clip,
                             const float* __restrict__ tok0, const float* __restrict__ tok1,
                             const float* __restrict__ cw, const float* __restrict__ cb,
                             const float* __restrict__ pos, float* __restrict__ x) {
  int row = blockIdx.x;
  int b = row / TT, t = row % TT;
  int d = threadIdx.x;
  float e;
  if (t == 0) {
    float acc = cb[d];
    for (int c = 0; c < CLIPN; ++c) acc = fmaf(clip[b*CLIPN + c], cw[c*DD + d], acc);
    e = acc;
  } else {
    int tok = idx[b*(TT-1) + (t-1)];
    e = (t <= SEMN) ? tok0[(size_t)tok*DD + d] : tok1[(size_t)tok*DD + d];
  }
  x[(size_t)row*DD + d] = e + pos[(size_t)t*DD + d];
}

// ---------------- layernorm: fp32 in -> bf16 out ----------------
__global__ __launch_bounds__(256) void ln_kernel(const float* __restrict__ x,
                                                 const float* __restrict__ g,
                                                 const float* __restrict__ bta,
                                                 __bf16* __restrict__ out) {
  int row = blockIdx.x;
  int tid = threadIdx.x;
  const float* xr = x + (size_t)row * DD;
  float v0 = xr[tid], v1 = xr[tid + 256];
  __shared__ float red[4];
  float s = v0 + v1;
  #pragma unroll
  for (int off = 32; off > 0; off >>= 1) s += __shfl_down(s, off);
  if ((tid & 63) == 0) red[tid >> 6] = s;
  __syncthreads();
  float mean = (red[0] + red[1] + red[2] + red[3]) * (1.0f / DD);
  float d0 = v0 - mean, d1 = v1 - mean;
  float sv = d0*d0 + d1*d1;
  #pragma unroll
  for (int off = 32; off > 0; off >>= 1) sv += __shfl_down(sv, off);
  __syncthreads();
  if ((tid & 63) == 0) red[tid >> 6] = sv;
  __syncthreads();
  float var = (red[0] + red[1] + red[2] + red[3]) * (1.0f / DD);
  float r = rsqrtf(var + 1e-5f);
  out[(size_t)row*DD + tid]       = (__bf16)(d0 * r * g[tid]       + bta[tid]);
  out[(size_t)row*DD + tid + 256] = (__bf16)(d1 * r * g[tid + 256] + bta[tid + 256]);
}

// ---------------- per-layer weight transpose+convert: [K,N] f32 -> [N,K] bf16 ----------------
__global__ __launch_bounds__(256) void prep_kernel(
    const float* __restrict__ wq, const float* __restrict__ wk,
    const float* __restrict__ wv, const float* __restrict__ wo,
    const float* __restrict__ w1, const float* __restrict__ w2,
    __bf16* __restrict__ wbuf) {
  __shared__ float tile[32][33];
  int id = blockIdx.x;
  const float* src; __bf16* dst; int K, N, t;
  if (id < 1024) {
    int m = id >> 8; t = id & 255;
    src = (m==0) ? wq : (m==1) ? wk : (m==2) ? wv : wo;
    dst = wbuf + (size_t)m * 262144; K = 512; N = 512;
  } else if (id < 2048) {
    t = id - 1024; src = w1; dst = wbuf + 1048576; K = 512; N = 2048;
  } else {
    t = id - 2048; src = w2; dst = wbuf + 2097152; K = 2048; N = 512;
  }
  int nsh = (N == 2048) ? 6 : 4;
  int tk = t >> nsh, tn = t & ((1 << nsh) - 1);
  int k0 = tk << 5, n0 = tn << 5;
  int tid = threadIdx.x;
  int r = tid >> 3, c = (tid & 7) << 2;
  float4 v = *(const float4*)&src[(size_t)(k0 + r)*N + n0 + c];
  tile[r][c+0] = v.x; tile[r][c+1] = v.y; tile[r][c+2] = v.z; tile[r][c+3] = v.w;
  __syncthreads();
  bf16x4 o;
  o[0] = (__bf16)tile[c+0][r];
  o[1] = (__bf16)tile[c+1][r];
  o[2] = (__bf16)tile[c+2][r];
  o[3] = (__bf16)tile[c+3][r];
  *(bf16x4*)&dst[(size_t)(n0 + r)*K + k0 + c] = o;
}

// ---------------- bf16 MFMA GEMM: C[M,N] = A[M,K] @ Bt[N,K]^T ----------------
// TM in {128,64}; TN = 128. QKV3: 3-way bias + V-cols written transposed to vtOut.
template<int TM, int QKV3, int RES, int GEL, int OB>
__global__ __launch_bounds__(256) void mgemm(
    const __bf16* __restrict__ A, const __bf16* __restrict__ Bt,
    const float* __restrict__ b0, const float* __restrict__ b1p, const float* __restrict__ b2p,
    const float* __restrict__ res, float* __restrict__ outF, __bf16* __restrict__ outB,
    __bf16* __restrict__ vtOut, int M, int N, int K, int ldo) {
  __shared__ __bf16 As[TM*32];
  __shared__ __bf16 Bs[128*32];
  int tid = threadIdx.x, wave = tid >> 6, l = tid & 63;
  int l15 = l & 15, lg = l >> 4;
  int m0 = blockIdx.y * TM, n0 = blockIdx.x << 7;
  constexpr int FM = 4;
  constexpr int FN = (TM == 128) ? 4 : 2;
  int wr = (TM == 128) ? (wave >> 1) : 0;
  int wc = (TM == 128) ? (wave & 1) : wave;

  f32x4 acc[FM][FN] = {};

  for (int k0 = 0; k0 < K; k0 += 32) {
#ifdef USE_GLL
    __syncthreads();    // previous tile consumed
    #pragma unroll
    for (int c = wave; c < TM/16; c += 4) {
      int row = c*16 + (l >> 2);
      int lslot = (l & 3) ^ ((row >> 1) & 3);
      gll16(A + (size_t)(m0+row)*K + k0 + lslot*8, &As[c*512]);
    }
    #pragma unroll
    for (int c = wave; c < 8; c += 4) {
      int row = c*16 + (l >> 2);
      int lslot = (l & 3) ^ ((row >> 1) & 3);
      gll16(Bt + (size_t)(n0+row)*K + k0 + lslot*8, &Bs[c*512]);
    }
    asm volatile("s_waitcnt vmcnt(0)" ::: "memory");
    __syncthreads();
#else
    bf16x8 ar[TM/64 > 0 ? TM/64 : 1], br[2];
    #pragma unroll
    for (int c = 0; c < TM/64; ++c) {
      int idx = tid + c*256;
      int row = idx >> 2;
      int lslot = (idx & 3) ^ ((row >> 1) & 3);
      ar[c] = *(const bf16x8*)(A + (size_t)(m0+row)*K + k0 + lslot*8);
    }
    #pragma unroll
    for (int c = 0; c < 2; ++c) {
      int idx = tid + c*256;
      int row = idx >> 2;
      int lslot = (idx & 3) ^ ((row >> 1) & 3);
      br[c] = *(const bf16x8*)(Bt + (size_t)(n0+row)*K + k0 + lslot*8);
    }
    __syncthreads();
    #pragma unroll
    for (int c = 0; c < TM/64; ++c) {
      int idx = tid + c*256;
      *(bf16x8*)&As[(idx >> 2)*32 + (idx & 3)*8] = ar[c];
    }
    #pragma unroll
    for (int c = 0; c < 2; ++c) {
      int idx = tid + c*256;
      *(bf16x8*)&Bs[(idx >> 2)*32 + (idx & 3)*8] = br[c];
    }
    __syncthreads();
#endif
    bf16x8 af[FM], bfr[FN];
    #pragma unroll
    for (int mi = 0; mi < FM; ++mi) {
      int row = (wr << 6) + (mi << 4) + l15;
      int ks = lg ^ ((row >> 1) & 3);
      af[mi] = *(const bf16x8*)&As[row*32 + (ks << 3)];
    }
    #pragma unroll
    for (int ni = 0; ni < FN; ++ni) {
      int row = wc*(FN*16) + (ni << 4) + l15;
      int ks = lg ^ ((row >> 1) & 3);
      bfr[ni] = *(const bf16x8*)&Bs[row*32 + (ks << 3)];
    }
    #pragma unroll
    for (int mi = 0; mi < FM; ++mi)
      #pragma unroll
      for (int ni = 0; ni < FN; ++ni)
        acc[mi][ni] = __builtin_amdgcn_mfma_f32_16x16x32_bf16(af[mi], bfr[ni], acc[mi][ni], 0, 0, 0);
  }

  #pragma unroll
  for (int mi = 0; mi < FM; ++mi) {
    #pragma unroll
    for (int ni = 0; ni < FN; ++ni) {
      int col = n0 + wc*(FN*16) + (ni << 4) + l15;
      float bs;
      if (QKV3) bs = (col < 512) ? b0[col] : (col < 1024) ? b1p[col-512] : b2p[col-1024];
      else bs = b0[col];
      int row0 = m0 + (wr << 6) + (mi << 4) + (lg << 2);
      if (QKV3 && col >= 1024) {
        // V columns: write transposed vt[bh][hd][key], key = token index
        int hdg = col - 1024;
        bf16x4 pk;
        #pragma unroll
        for (int r = 0; r < 4; ++r) pk[r] = (__bf16)(acc[mi][ni][r] + bs);
        size_t vrow = (size_t)(((row0 >> 11)*8 + (hdg >> 6))*64 + (hdg & 63));
        *(bf16x4*)&vtOut[vrow*VST + (row0 & 2047)] = pk;
      } else {
        #pragma unroll
        for (int r = 0; r < 4; ++r) {
          int row = row0 + r;
          float v = acc[mi][ni][r] + bs;
          if (RES) v += res[(size_t)row*ldo + col];
          if (GEL) v = 0.5f * v * (1.0f + erff(v * 0.70710678118654752f));
          if (OB) outB[(size_t)row*ldo + col] = (__bf16)v;
          else    outF[(size_t)row*ldo + col] = v;
        }
      }
    }
  }
}

// ---------------- flash attention, 4 waves/block = 4-way key-split of one (b,h,16q) unit ----------------
// swapped QK^T: S^T = mfma(A=K, B=Q). K and V^T direct global->reg (L2-resident).
// Waves run barrier-free through their key chunk; single __syncthreads + LDS flash-merge.
__global__ __launch_bounds__(256) void attn_kernel(const __bf16* __restrict__ qkv,
                                                   const __bf16* __restrict__ vt,
                                                   __bf16* __restrict__ y) {
  __shared__ __bf16 Pall[4][16*32];       // per-wave P round-trip
  __shared__ float po[4][16][68];         // partial O [wave][q][hd], padded
  __shared__ float pmS[4][16], plS[4][16];
  int tid = threadIdx.x, wave = tid >> 6, l = tid & 63;
  int l15 = l & 15, lg = l >> 4;
  __bf16* Pl = Pall[wave];
  int xsw = (l15 >> 1) & 3;               // P-slot XOR key (pairs rows per bank window)

  int wid = blockIdx.x;                // 0..2047, longest-first
  int g  = 127 - (wid >> 4);           // q-group (16 rows) within (b,h)
  int bh = wid & 15;
  int b = bh >> 3, h = bh & 7;

  const __bf16* qp = qkv + (size_t)(b*TT)*QS + h*HDD;
  const __bf16* kp = qp + 512;
  const __bf16* vtp = vt + ((size_t)bh*64 + l15)*VST + lg*8;
  const __bf16* kbase = kp + (size_t)l15*QS + lg*8;

  // Q B-fragment (col=q=l15, k=hd=lg*8+e), pre-scaled by 1/sqrt(64)
  bf16x8 qf0, qf1;
  {
    size_t qr = (size_t)(g*16 + l15) * QS + lg*8;
    bf16x8 t0 = *(const bf16x8*)(qp + qr);
    bf16x8 t1 = *(const bf16x8*)(qp + qr + 32);
    #pragma unroll
    for (int e = 0; e < 8; ++e) {
      qf0[e] = (__bf16)((float)t0[e] * 0.125f);
      qf1[e] = (__bf16)((float)t1[e] * 0.125f);
    }
  }

  f32x4 o[4] = {};
  float m = -1e30f, lsum = 0.f;
  int qpos = g*16 + l15;
  int nt = (16*g + 47) >> 5;           // total 32-key tiles for this unit
  int cs = (nt + 3) >> 2;              // chunk size per wave
  int t0 = wave * cs;
  int t1 = t0 + cs; if (t1 > nt) t1 = nt;

  auto kload = [&](int kt, bf16x8& k00, bf16x8& k01, bf16x8& k10, bf16x8& k11,
                   bf16x8& v0, bf16x8& v1, bf16x8& v2, bf16x8& v3) {
    const __bf16* kr = kbase + (size_t)kt*32*QS;
    k00 = *(const bf16x8*)(kr);
    k01 = *(const bf16x8*)(kr + 32);
    k10 = *(const bf16x8*)(kr + 16*QS);
    k11 = *(const bf16x8*)(kr + 16*QS + 32);
    const __bf16* vr = vtp + kt*32;
    v0 = *(const bf16x8*)(vr);
    v1 = *(const bf16x8*)(vr + 16*VST);
    v2 = *(const bf16x8*)(vr + 32*VST);
    v3 = *(const bf16x8*)(vr + 48*VST);
  };

  auto process = [&](int kt, bf16x8 k00, bf16x8 k01, bf16x8 k10, bf16x8 k11,
                     bf16x8 v0, bf16x8 v1, bf16x8 v2, bf16x8 v3) {
    // S^T = K @ Q^T : rows=key (kb*16+lg*4+r), cols=q (l15)
    f32x4 s0 = {}, s1 = {};
    s0 = __builtin_amdgcn_mfma_f32_16x16x32_bf16(k00, qf0, s0, 0, 0, 0);
    s0 = __builtin_amdgcn_mfma_f32_16x16x32_bf16(k01, qf1, s0, 0, 0, 0);
    s1 = __builtin_amdgcn_mfma_f32_16x16x32_bf16(k10, qf0, s1, 0, 0, 0);
    s1 = __builtin_amdgcn_mfma_f32_16x16x32_bf16(k11, qf1, s1, 0, 0, 0);

    int kb0 = kt*32 + lg*4;
    float sv0[4], sv1[4];
    #pragma unroll
    for (int r = 0; r < 4; ++r) {
      sv0[r] = (kb0 + r      <= qpos) ? s0[r] : -1e30f;
      sv1[r] = (kb0 + 16 + r <= qpos) ? s1[r] : -1e30f;
    }

    // tile max per q (in-lane over 8 keys, cross-lane over lg)
    float tmax = fmaxf(fmaxf(fmaxf(sv0[0],sv0[1]), fmaxf(sv0[2],sv0[3])),
                       fmaxf(fmaxf(sv1[0],sv1[1]), fmaxf(sv1[2],sv1[3])));
    tmax = fmaxf(tmax, __shfl_xor(tmax, 16));
    tmax = fmaxf(tmax, __shfl_xor(tmax, 32));

    // defer-max (T13, THR=8): skip O-rescale when max growth small
    if (!__all(tmax - m <= 8.0f)) {
      float mn = fmaxf(m, tmax);
      float fac = __expf(m - mn);
      m = mn;
      lsum *= fac;
      float f0 = __shfl(fac, lg*4+0), f1 = __shfl(fac, lg*4+1);
      float f2 = __shfl(fac, lg*4+2), f3 = __shfl(fac, lg*4+3);
      #pragma unroll
      for (int hc = 0; hc < 4; ++hc) {
        o[hc][0] *= f0; o[hc][1] *= f1; o[hc][2] *= f2; o[hc][3] *= f3;
      }
    }

    // guard: meff keeps exp() well-defined for fully-masked q rows (m = -1e30)
    float meff = fmaxf(m, -1e20f);
    float rsum = 0.f;
    bf16x4 pk0, pk1;
    #pragma unroll
    for (int r = 0; r < 4; ++r) {
      float p0 = __expf(sv0[r] - meff);
      float p1 = __expf(sv1[r] - meff);
      rsum += p0 + p1;
      pk0[r] = (__bf16)p0;
      pk1[r] = (__bf16)p1;
    }
    rsum += __shfl_xor(rsum, 16);
    rsum += __shfl_xor(rsum, 32);
    lsum += rsum;

    // P^T -> P via wave-private LDS, 16B-slot XOR swizzle (stride 32)
    int s0i = ((lg >> 1)    ) ^ xsw;
    int s1i = ((lg >> 1) + 2) ^ xsw;
    *(bf16x4*)&Pl[l15*32 + s0i*8 + (lg & 1)*4] = pk0;
    *(bf16x4*)&Pl[l15*32 + s1i*8 + (lg & 1)*4] = pk1;
    asm volatile("s_waitcnt lgkmcnt(0)" ::: "memory");
    __builtin_amdgcn_sched_barrier(0);
    bf16x8 pa = *(const bf16x8*)&Pl[l15*32 + ((lg ^ xsw)*8)];

    // O += P @ V : A=P[q=l15][k=key], B=V^T (k=key, col=hd=hc*16+l15)
    o[0] = __builtin_amdgcn_mfma_f32_16x16x32_bf16(pa, v0, o[0], 0, 0, 0);
    o[1] = __builtin_amdgcn_mfma_f32_16x16x32_bf16(pa, v1, o[1], 0, 0, 0);
    o[2] = __builtin_amdgcn_mfma_f32_16x16x32_bf16(pa, v2, o[2], 0, 0, 0);
    o[3] = __builtin_amdgcn_mfma_f32_16x16x32_bf16(pa, v3, o[3], 0, 0, 0);
  };

  if (t0 < t1) {
    bf16x8 a00,a01,a10,a11,av0,av1,av2,av3;
    bf16x8 b00,b01,b10,b11,bv0,bv1,bv2,bv3;
    kload(t0, a00,a01,a10,a11, av0,av1,av2,av3);
    for (int kt = t0; kt < t1; ) {
      if (kt + 1 < t1) kload(kt+1, b00,b01,b10,b11, bv0,bv1,bv2,bv3);
      process(kt, a00,a01,a10,a11, av0,av1,av2,av3);
      ++kt; if (kt >= t1) break;
      if (kt + 1 < t1) kload(kt+1, a00,a01,a10,a11, av0,av1,av2,av3);
      process(kt, b00,b01,b10,b11, bv0,bv1,bv2,bv3);
      ++kt;
    }
  }

  // ---- write partials ----
  #pragma unroll
  for (int hc = 0; hc < 4; ++hc)
    #pragma unroll
    for (int r = 0; r < 4; ++r)
      po[wave][lg*4 + r][hc*16 + l15] = o[hc][r];
  if (l < 16) { pmS[wave][l] = m; plS[wave][l] = lsum; }
  __syncthreads();

  // ---- flash merge: wave handles q rows wave*4+lg; lane covers hd = l15*4..+4 ----
  {
    int q = wave*4 + lg;
    float m0 = pmS[0][q], m1 = pmS[1][q], m2 = pmS[2][q], m3 = pmS[3][q];
    float mstar = fmaxf(fmaxf(m0, m1), fmaxf(m2, m3));
    float f0 = __expf(m0 - mstar), f1 = __expf(m1 - mstar);
    float f2 = __expf(m2 - mstar), f3 = __expf(m3 - mstar);
    float lstar = plS[0][q]*f0 + plS[1][q]*f1 + plS[2][q]*f2 + plS[3][q]*f3;
    float inv = 1.0f / lstar;
    f32x4 o0 = *(const f32x4*)&po[0][q][l15*4];
    f32x4 o1 = *(const f32x4*)&po[1][q][l15*4];
    f32x4 o2 = *(const f32x4*)&po[2][q][l15*4];
    f32x4 o3 = *(const f32x4*)&po[3][q][l15*4];
    bf16x4 out;
    #pragma unroll
    for (int j = 0; j < 4; ++j)
      out[j] = (__bf16)((o0[j]*f0 + o1[j]*f1 + o2[j]*f2 + o3[j]*f3) * inv);
    size_t base = (size_t)(b*TT + g*16 + q) * DD + h*HDD + l15*4;
    *(bf16x4*)&y[base] = out;
  }
}

extern "C" void kernel_launch(void* const* d_in, const int* in_sizes, int n_in,
                              void* d_out, int out_size, void* d_ws, size_t ws_size,
                              hipStream_t stream) {
  const int*   idx    = (const int*)d_in[0];
  const float* clip   = (const float*)d_in[1];
  const float* tok0   = (const float*)d_in[2];
  const float* tok1   = (const float*)d_in[3];
  const float* cond_w = (const float*)d_in[4];
  const float* cond_b = (const float*)d_in[5];
  const float* pos    = (const float*)d_in[6];
  const float* ln1_g  = (const float*)d_in[7];
  const float* ln1_b  = (const float*)d_in[8];
  const float* wq     = (const float*)d_in[9];
  const float* bq     = (const float*)d_in[10];
  const float* wk     = (const float*)d_in[11];
  const float* bk     = (const float*)d_in[12];
  const float* wv     = (const float*)d_in[13];
  const float* bv     = (const float*)d_in[14];
  const float* wo     = (const float*)d_in[15];
  const float* bo     = (const float*)d_in[16];
  const float* ln2_g  = (const float*)d_in[17];
  const float* ln2_b  = (const float*)d_in[18];
  const float* w1     = (const float*)d_in[19];
  const float* b1     = (const float*)d_in[20];
  const float* w2     = (const float*)d_in[21];
  const float* b2     = (const float*)d_in[22];

  float* x = (float*)d_out;
  char* wsb = (char*)d_ws;
  __bf16* wbuf = (__bf16*)wsb;                       // 6,291,456 B: [wq^T wk^T wv^T wo^T w1^T w2^T] bf16
  __bf16* h    = (__bf16*)(wsb + 6291456);           // 4 MB ln out
  __bf16* qkv  = (__bf16*)(wsb + 10485760);          // 8 MB (4096 x 1024: Q|K)
  __bf16* yb   = (__bf16*)(wsb + 23068672);          // 4 MB attn out (ends 27,262,976)
  __bf16* ffn  = qkv;                                // 16 MB alias (qkv..yb dead by then)
  __bf16* vt   = (__bf16*)(wsb + 27262976);          // 4,210,688 B: [16 bh][64 hd][2056]

  embed_kernel<<<dim3(NTOK), 512, 0, stream>>>(idx, clip, tok0, tok1, cond_w, cond_b, pos, x);

  for (int i = 0; i < LL; ++i) {
    prep_kernel<<<dim3(3072), 256, 0, stream>>>(
        wq + (size_t)i*262144, wk + (size_t)i*262144, wv + (size_t)i*262144,
        wo + (size_t)i*262144, w1 + (size_t)i*1048576, w2 + (size_t)i*1048576, wbuf);

    ln_kernel<<<NTOK, 256, 0, stream>>>(x, ln1_g + i*DD, ln1_b + i*DD, h);

    mgemm<128,1,0,0,1><<<dim3(12, 32), 256, 0, stream>>>(
        h, wbuf, bq + i*DD, bk + i*DD, bv + i*DD, nullptr, nullptr, qkv, vt, NTOK, 1536, 512, 1024);

    attn_kernel<<<dim3(2048), 256, 0, stream>>>(qkv, vt, yb);

    mgemm<64,0,1,0,0><<<dim3(4, 64), 256, 0, stream>>>(
        yb, wbuf + 786432, bo + i*DD, nullptr, nullptr, x, x, nullptr, nullptr, NTOK, 512, 512, 512);

    ln_kernel<<<NTOK, 256, 0, stream>>>(x, ln2_g + i*DD, ln2_b + i*DD, h);

    mgemm<128,0,0,1,1><<<dim3(16, 32), 256, 0, stream>>>(
        h, wbuf + 1048576, b1 + (size_t)i*4*DD, nullptr, nullptr, nullptr, nullptr, ffn, nullptr, NTOK, 4*DD, 512, 2048);

    mgemm<64,0,1,0,0><<<dim3(4, 64), 256, 0, stream>>>(
        ffn, wbuf + 2097152, b2 + i*DD, nullptr, nullptr, x, x, nullptr, nullptr, NTOK, 512, 2048, 512);
  }
}